// Round 2
// baseline (1558.401 us; speedup 1.0000x reference)
//
#include <hip/hip_runtime.h>
#include <hip/hip_bf16.h>

#define NN 100000
#define NEG 1600000
#define DD 256
#define DOUT 128

typedef unsigned short u16;
typedef unsigned int u32;
typedef __attribute__((ext_vector_type(8))) __bf16 bf16x8;
typedef __attribute__((ext_vector_type(4))) float f32x4;
typedef __attribute__((ext_vector_type(4))) unsigned int u32x4;

__device__ __forceinline__ float b2f(u16 b){ u32 u=((u32)b)<<16; float f; __builtin_memcpy(&f,&u,4); return f; }
__device__ __forceinline__ u16 f2b(float f){ u32 u; __builtin_memcpy(&u,&f,4); u32 r=(u + 0x7FFFu + ((u>>16)&1u))>>16; return (u16)r; }
__device__ __forceinline__ u32 pack2(float a, float b){ return (u32)f2b(a) | ((u32)f2b(b)<<16); }

// ---- forced-issue global load (cannot be sunk/serialized by the compiler) ----
__device__ __forceinline__ u32x4 gld(const u16* p){
  u32x4 r;
  asm volatile("global_load_dwordx4 %0, %1, off" : "=v"(r) : "v"(p));
  return r;
}
template<int N>
__device__ __forceinline__ void s_wait_vm(){
  asm volatile("s_waitcnt vmcnt(%0)" :: "n"(N) : "memory");
  __builtin_amdgcn_sched_barrier(0);
}
__device__ __forceinline__ void wave_barrier(){
  asm volatile("s_waitcnt lgkmcnt(0)" ::: "memory");
  __builtin_amdgcn_sched_barrier(0);
  __builtin_amdgcn_s_barrier();
}
__device__ __forceinline__ f32x4 mfma16(u32x4 a, u32x4 b, f32x4 c){
  return __builtin_amdgcn_mfma_f32_16x16x32_bf16(
    __builtin_bit_cast(bf16x8,a), __builtin_bit_cast(bf16x8,b), c, 0,0,0);
}

// ---------------- weight transpose (fp32 [256][ncols] -> bf16 [ncols][256]) ----------------
__global__ void k_wtrans(const float* __restrict__ W, u16* __restrict__ WT, int ncols){
  int n = blockIdx.x; int k = threadIdx.x;
  WT[n*DD + k] = f2b(W[k*ncols + n]);
}

// ---------------- fp32 -> bf16 bulk convert (x) ----------------
__global__ void k_f2bv(const float* __restrict__ in, u16* __restrict__ out){
  long long i = (long long)(blockIdx.x*256 + threadIdx.x) * 8;
  if(i >= (long long)NN*DD) return;
  float4 a = *(const float4*)&in[i];
  float4 b = *(const float4*)&in[i+4];
  uint4 sv;
  sv.x = pack2(a.x,a.y); sv.y = pack2(a.z,a.w);
  sv.z = pack2(b.x,b.y); sv.w = pack2(b.z,b.w);
  *(uint4*)&out[i] = sv;
}

// ---------------- graph prep ----------------
__global__ void k_deg(const int* __restrict__ ei, int* __restrict__ deg){
  int e = blockIdx.x*256 + threadIdx.x;
  if(e < NEG) atomicAdd(&deg[ei[NEG + e]], 1);
}

__global__ void k_scan_a(const int* __restrict__ deg, int* __restrict__ part){
  __shared__ int s[256];
  int i = blockIdx.x*256 + threadIdx.x;
  int v = (i < NN) ? deg[i] : 0;
  s[threadIdx.x] = v; __syncthreads();
  for(int o=128;o>0;o>>=1){ if(threadIdx.x<o) s[threadIdx.x]+=s[threadIdx.x+o]; __syncthreads(); }
  if(threadIdx.x==0) part[blockIdx.x]=s[0];
}

__global__ void k_scan_b(int* __restrict__ part){
  __shared__ int s[512];
  int tx = threadIdx.x;
  int v = (tx < 391) ? part[tx] : 0;
  s[tx] = v; __syncthreads();
  for(int o=1;o<512;o<<=1){ int t=(tx>=o)?s[tx-o]:0; __syncthreads(); s[tx]+=t; __syncthreads(); }
  if(tx < 391) part[tx] = s[tx]-v;  // exclusive
}

__global__ void k_scan_c(const int* __restrict__ deg, const int* __restrict__ part,
                         int* __restrict__ rowstart, int* __restrict__ cursor, float* __restrict__ dsq){
  __shared__ int s[256];
  int tx = threadIdx.x;
  int i = blockIdx.x*256 + tx;
  int v = (i < NN) ? deg[i] : 0;
  s[tx]=v; __syncthreads();
  for(int o=1;o<256;o<<=1){ int t=(tx>=o)?s[tx-o]:0; __syncthreads(); s[tx]+=t; __syncthreads(); }
  int incl = s[tx];
  int base = part[blockIdx.x];
  if(i < NN){
    int excl = base + incl - v;
    rowstart[i]=excl; cursor[i]=excl;
    dsq[i] = (v>0) ? rsqrtf((float)v) : 0.f;
    if(i == NN-1) rowstart[NN] = base + incl;
  }
}

__global__ void k_csr(const int* __restrict__ ei, int* __restrict__ cursor, int* __restrict__ csr_row){
  int e = blockIdx.x*256 + threadIdx.x;
  if(e < NEG){
    int r = ei[e], c = ei[NEG + e];
    int p = atomicAdd(&cursor[c], 1);
    csr_row[p] = r;
  }
}

// ---------------- BN helpers ----------------
__global__ void k_bnprep(const float* __restrict__ cs, const float* __restrict__ cq,
                         const float* __restrict__ g, const float* __restrict__ b,
                         float* __restrict__ scale, float* __restrict__ shift){
  int c = threadIdx.x;
  float m = cs[c] * (1.0f/NN);
  float var = cq[c] * (1.0f/NN) - m*m;
  float rs = rsqrtf(var + 1e-5f);
  float sc = g[c]*rs;
  scale[c] = sc; shift[c] = b[c] - m*sc;
}

__global__ void k_bnrelu(const u16* __restrict__ yg, const float* __restrict__ scale,
                         const float* __restrict__ shift, u16* __restrict__ g0){
  long long i = (long long)(blockIdx.x*256 + threadIdx.x) * 8;
  if(i >= (long long)NN*DD) return;
  int c0 = (int)(i & 255);
  uint4 v = *(const uint4*)&yg[i];
  const u16* p = (const u16*)&v;
  u32 w[4];
  #pragma unroll
  for(int j=0;j<4;j++){
    float a = fmaxf(b2f(p[2*j  ])*scale[c0+2*j  ]+shift[c0+2*j  ], 0.f);
    float b_ = fmaxf(b2f(p[2*j+1])*scale[c0+2*j+1]+shift[c0+2*j+1], 0.f);
    w[j] = pack2(a,b_);
  }
  uint4 sv; sv.x=w[0]; sv.y=w[1]; sv.z=w[2]; sv.w=w[3];
  *(uint4*)&g0[i] = sv;
}

// ---------------- CSR gather ----------------
__global__ __launch_bounds__(256) void k_gather(const u16* __restrict__ g0, const int* __restrict__ rowstart,
                                                const int* __restrict__ csr_row, const float* __restrict__ dsq,
                                                u16* __restrict__ agg){
  int node = blockIdx.x*8 + (threadIdx.x>>5);
  int lane = threadIdx.x & 31;
  if(node >= NN) return;
  int s = rowstart[node], e = rowstart[node+1];
  float di = dsq[node];
  int d0 = lane*8;
  float acc[8] = {0,0,0,0,0,0,0,0};
  int j = s;
  for(; j+1 < e; j += 2){
    int r0 = csr_row[j], r1 = csr_row[j+1];
    float w0 = di*dsq[r0], w1 = di*dsq[r1];
    uint4 a = *(const uint4*)&g0[(size_t)r0*DD + d0];
    uint4 b = *(const uint4*)&g0[(size_t)r1*DD + d0];
    const u16* pa = (const u16*)&a; const u16* pb = (const u16*)&b;
    #pragma unroll
    for(int t=0;t<8;t++){ acc[t] += w0*b2f(pa[t]); acc[t] += w1*b2f(pb[t]); }
  }
  if(j < e){
    int r0 = csr_row[j]; float w0 = di*dsq[r0];
    uint4 a = *(const uint4*)&g0[(size_t)r0*DD + d0];
    const u16* pa = (const u16*)&a;
    #pragma unroll
    for(int t=0;t<8;t++) acc[t] += w0*b2f(pa[t]);
  }
  u32 w[4];
  #pragma unroll
  for(int t=0;t<4;t++) w[t] = pack2(acc[2*t], acc[2*t+1]);
  uint4 sv; sv.x=w[0]; sv.y=w[1]; sv.z=w[2]; sv.w=w[3];
  *(uint4*)&agg[(size_t)node*DD + d0] = sv;
}

enum { EP_LN=0, EP_QN=1, EP_KT=2, EP_VT=3, EP_CS=4, EP_AT=5, EP_OUTP=6, EP_KV=7 };

// ---------------- legacy LDS-staged GEMM (kept only for EP_KV: K=100000 reduction) ----------------
template<int EP, bool AF32, int NCOLS>
__global__ __launch_bounds__(256,2)
void k_gemm(const void* __restrict__ Ap, const u16* __restrict__ BT,
            const float* __restrict__ bias,
            u16* __restrict__ outb, float* __restrict__ outf,
            int kSteps, int kLimit, int Astride, int Bstride, int Mlim)
{
  constexpr int NT = NCOLS/64;
  const int tid = threadIdx.x;
  const int wave = tid>>6, lane = tid&63, quad = lane>>4, l15 = lane&15;
  const int m0 = blockIdx.x*64;
  const int kBase = blockIdx.y*(kSteps*32);
  const int wb = wave*(NCOLS/4);

  __shared__ __align__(16) u16 As[64][48];
  __shared__ __align__(16) u16 Bs[NCOLS][48];

  f32x4 acc[4][NT];
  #pragma unroll
  for(int i=0;i<4;i++)
    #pragma unroll
    for(int j=0;j<NT;j++){ acc[i][j][0]=0.f; acc[i][j][1]=0.f; acc[i][j][2]=0.f; acc[i][j][3]=0.f; }

  for(int st=0; st<kSteps; st++){
    const int k0 = kBase + st*32;
    __syncthreads();
    {
      const u16* Ab = (const u16*)Ap;
      int row=tid>>2, seg=tid&3, gr=m0+row, gk=k0+seg*8;
      uint4 v = make_uint4(0u,0u,0u,0u);
      if(gr<Mlim && gk<kLimit) v = *(const uint4*)&Ab[(size_t)gr*Astride+gk];
      *(uint4*)&As[row][seg*8] = v;
    }
    #pragma unroll
    for(int it=0; it<NCOLS/64; it++){
      int s=tid+it*256, row=s>>2, seg=s&3, gk=k0+seg*8;
      uint4 v = make_uint4(0u,0u,0u,0u);
      if(gk<kLimit) v = *(const uint4*)&BT[(size_t)row*Bstride+gk];
      *(uint4*)&Bs[row][seg*8] = v;
    }
    __syncthreads();
    uint4 afu[4]; uint4 bfu[NT];
    #pragma unroll
    for(int mi=0;mi<4;mi++) afu[mi] = *(const uint4*)&As[mi*16+l15][quad*8];
    #pragma unroll
    for(int ni=0;ni<NT;ni++) bfu[ni] = *(const uint4*)&Bs[wb+ni*16+l15][quad*8];
    #pragma unroll
    for(int mi=0;mi<4;mi++)
      #pragma unroll
      for(int ni=0;ni<NT;ni++)
        acc[mi][ni] = __builtin_amdgcn_mfma_f32_16x16x32_bf16(
            __builtin_bit_cast(bf16x8, afu[mi]),
            __builtin_bit_cast(bf16x8, bfu[ni]),
            acc[mi][ni], 0,0,0);
  }

  #pragma unroll
  for(int mi=0;mi<4;mi++)
    #pragma unroll
    for(int r=0;r<4;r++){
      int gr = m0 + mi*16 + quad*4 + r;
      if(gr<Mlim){
        #pragma unroll
        for(int ni=0;ni<NT;ni++) atomicAdd(&outf[(size_t)gr*DD + wb+ni*16+l15], acc[mi][ni][r]);
      }
    }
}

// ---------------- strip-pipelined streaming GEMM engine ----------------
// 512 thr = 8 waves x 32 cols (N=256). B panel in 64 VGPRs/wave. A streamed via
// volatile-asm clustered loads, double-buffered per 16-row strip, counted vmcnt.
// K=256 fully consumed per strip -> per-strip epilogue. Raw barriers (no vmcnt drain).
template<int EP>
__global__ __launch_bounds__(512,2)
void k_rg(const u16* __restrict__ Ab, const u16* __restrict__ BT,
          const float* __restrict__ bias, u16* __restrict__ outb,
          const float* __restrict__ p0, const float* __restrict__ p1,
          const float* __restrict__ p2, const float* __restrict__ p3,
          const u16* __restrict__ hb,
          float* __restrict__ st0, float* __restrict__ st1)
{
  constexpr bool TRS = (EP==EP_KT||EP==EP_VT);
  const int tid = threadIdx.x;
  const int wave = tid>>6, lane = tid&63, quad = lane>>4, l15 = lane&15;
  const int m0 = blockIdx.x*64;
  const int wb = wave*32;
  const int col0 = wb+l15, col1 = wb+16+l15;

  __shared__ float red[2][2][8][16];
  __shared__ float dls[2][16];
  __shared__ u16 Ts[TRS?64:1][DD+2];   // stride 258 u16 -> conflict-free transpose read

  // ---- B panel: 32 cols x 256 K resident (64 VGPRs) ----
  u32x4 bf0[8], bf1[8];
  {
    const u16* b0p = &BT[(size_t)col0*DD + quad*8];
    const u16* b1p = &BT[(size_t)col1*DD + quad*8];
    #pragma unroll
    for(int ks=0;ks<8;ks++){ bf0[ks]=*(const u32x4*)(b0p+ks*32); bf1[ks]=*(const u32x4*)(b1p+ks*32); }
  }
  float bv0 = bias? bias[col0]:0.f, bv1 = bias? bias[col1]:0.f;
  float g0c=0.f,g1c=0.f,b0c=0.f,b1c=0.f;
  if constexpr (EP==EP_LN||EP==EP_AT){ g0c=p0[col0]; g1c=p0[col1]; b0c=p1[col0]; b1c=p1[col1]; }
  float vs0=0.f, vs1=0.f;
  if constexpr (EP==EP_AT){ vs0=p3[col0]; vs1=p3[col1]; }

  auto rowp = [&](int mi){ int gr=m0+mi*16+l15; if(gr>=NN) gr=NN-1; return &Ab[(size_t)gr*DD+(size_t)(quad*8)]; };
  const u16 *ab0=rowp(0), *ab1=rowp(1), *ab2=rowp(2), *ab3=rowp(3);

  float csA=0.f,csB=0.f,cqA=0.f,cqB=0.f;   // col-stat accumulators (CS / KT / VT)

  auto pref = [&](u32x4 (&B)[8], const u16* p){
    #pragma unroll
    for(int ks=0;ks<8;ks++) B[ks]=gld(p+ks*32);
  };
  f32x4 a0,a1;
  auto comp = [&](u32x4 (&B)[8]){
    f32x4 z={0.f,0.f,0.f,0.f}; a0=z; a1=z;
    #pragma unroll
    for(int ks=0;ks<8;ks++){ a0=mfma16(B[ks],bf0[ks],a0); a1=mfma16(B[ks],bf1[ks],a1); }
  };
  auto dotf = [&](u32x4 (&B)[8])->float{
    if constexpr (EP!=EP_AT) { (void)B; return 0.f; }
    else {
      float d=0.f;
      #pragma unroll
      for(int ks=0;ks<8;ks++){
        const u16* ax=(const u16*)&B[ks];
        float4 kA=*(const float4*)&p2[ks*32+quad*8];
        float4 kB=*(const float4*)&p2[ks*32+quad*8+4];
        d += b2f(ax[0])*kA.x + b2f(ax[1])*kA.y + b2f(ax[2])*kA.z + b2f(ax[3])*kA.w;
        d += b2f(ax[4])*kB.x + b2f(ax[5])*kB.y + b2f(ax[6])*kB.z + b2f(ax[7])*kB.w;
      }
      d += __shfl_xor(d,16); d += __shfl_xor(d,32);
      return d;
    }
  };

  auto epi = [&](int mi, float dotv){
    const int slot = mi&1;
    if constexpr (EP==EP_CS){
      #pragma unroll
      for(int r=0;r<4;r++){
        int gr=m0+mi*16+quad*4+r;
        if(gr<NN){
          float v0=a0[r]+bv0, v1=a1[r]+bv1;
          outb[(size_t)gr*DD+col0]=f2b(v0);
          outb[(size_t)gr*DD+col1]=f2b(v1);
          csA+=v0; cqA+=v0*v0; csB+=v1; cqB+=v1*v1;
        }
      }
    }
    if constexpr (EP==EP_VT){
      #pragma unroll
      for(int r=0;r<4;r++){
        int row=quad*4+r, gr=m0+mi*16+row;
        float v0=(gr<NN)?a0[r]+bv0:0.f;
        float v1=(gr<NN)?a1[r]+bv1:0.f;
        csA+=v0; csB+=v1;
        Ts[mi*16+row][col0]=f2b(v0);
        Ts[mi*16+row][col1]=f2b(v1);
      }
    }
    if constexpr (EP==EP_QN||EP==EP_KT){
      #pragma unroll
      for(int r=0;r<4;r++){
        float v0=a0[r]+bv0, v1=a1[r]+bv1;
        float s2=v0*v0+v1*v1;
        #pragma unroll
        for(int o=1;o<16;o<<=1) s2+=__shfl_xor(s2,o);
        if(l15==0) red[slot][0][wave][quad*4+r]=s2;
      }
      wave_barrier();
      #pragma unroll
      for(int r=0;r<4;r++){
        int row=quad*4+r, gr=m0+mi*16+row;
        float S2=0.f;
        #pragma unroll
        for(int w=0;w<8;w++) S2+=red[slot][0][w][row];
        float rsr=rsqrtf(S2);
        if constexpr (EP==EP_QN){
          if(gr<NN){
            outb[(size_t)gr*DD+col0]=f2b((a0[r]+bv0)*rsr);
            outb[(size_t)gr*DD+col1]=f2b((a1[r]+bv1)*rsr);
          }
        } else {
          float v0=(gr<NN)?(a0[r]+bv0)*rsr:0.f;
          float v1=(gr<NN)?(a1[r]+bv1)*rsr:0.f;
          csA+=v0; csB+=v1;
          Ts[mi*16+row][col0]=f2b(v0);
          Ts[mi*16+row][col1]=f2b(v1);
        }
      }
    }
    if constexpr (EP==EP_AT){
      if(wave==0 && quad==0) dls[slot][l15]=dotv+200000.0f;   // + 2*nf
      wave_barrier();
      float vv0[4], vv1[4];
      #pragma unroll
      for(int r=0;r<4;r++){
        int row=quad*4+r, gr=m0+mi*16+row;
        float den=dls[slot][row];
        size_t rb=(size_t)(gr<NN?gr:NN-1)*DD;
        float hv0=b2f(hb[rb+col0]), hv1=b2f(hb[rb+col1]);
        vv0[r]=((a0[r]+100000.0f*vs0)/den + hv0)*0.5f;
        vv1[r]=((a1[r]+100000.0f*vs1)/den + hv1)*0.5f;
      }
      #pragma unroll
      for(int r=0;r<4;r++){
        float s=vv0[r]+vv1[r], s2=vv0[r]*vv0[r]+vv1[r]*vv1[r];
        #pragma unroll
        for(int o=1;o<16;o<<=1){ s+=__shfl_xor(s,o); s2+=__shfl_xor(s2,o); }
        if(l15==0){ red[slot][0][wave][quad*4+r]=s; red[slot][1][wave][quad*4+r]=s2; }
      }
      wave_barrier();
      #pragma unroll
      for(int r=0;r<4;r++){
        int row=quad*4+r, gr=m0+mi*16+row;
        if(gr<NN){
          float S=0.f,S2=0.f;
          #pragma unroll
          for(int w=0;w<8;w++){ S+=red[slot][0][w][row]; S2+=red[slot][1][w][row]; }
          float mean=S*(1.0f/DD), var=S2*(1.0f/DD)-mean*mean, rstd=rsqrtf(var+1e-5f);
          float v0=(vv0[r]-mean)*rstd*g0c+b0c;
          float v1=(vv1[r]-mean)*rstd*g1c+b1c;
          outb[(size_t)gr*DD+col0]=f2b(fmaxf(v0,0.f));
          outb[(size_t)gr*DD+col1]=f2b(fmaxf(v1,0.f));
        }
      }
    }
    if constexpr (EP==EP_LN){
      #pragma unroll
      for(int r=0;r<4;r++){
        float v0=a0[r]+bv0, v1=a1[r]+bv1;
        float s=v0+v1, s2=v0*v0+v1*v1;
        #pragma unroll
        for(int o=1;o<16;o<<=1){ s+=__shfl_xor(s,o); s2+=__shfl_xor(s2,o); }
        if(l15==0){ red[slot][0][wave][quad*4+r]=s; red[slot][1][wave][quad*4+r]=s2; }
      }
      wave_barrier();
      #pragma unroll
      for(int r=0;r<4;r++){
        int row=quad*4+r, gr=m0+mi*16+row;
        if(gr<NN){
          float S=0.f,S2=0.f;
          #pragma unroll
          for(int w=0;w<8;w++){ S+=red[slot][0][w][row]; S2+=red[slot][1][w][row]; }
          float mean=S*(1.0f/DD), var=S2*(1.0f/DD)-mean*mean, rstd=rsqrtf(var+1e-5f);
          float v0=(a0[r]+bv0-mean)*rstd*g0c+b0c;
          float v1=(a1[r]+bv1-mean)*rstd*g1c+b1c;
          outb[(size_t)gr*DD+col0]=f2b(fmaxf(v0,0.f));
          outb[(size_t)gr*DD+col1]=f2b(fmaxf(v1,0.f));
        }
      }
    }
  };

  // ---- strip pipeline: prefetch(next) -> vmcnt(8) -> MFMA(cur) -> epilogue(cur) ----
  u32x4 bA[8], bB[8];
  pref(bA,ab0);
  pref(bB,ab1); s_wait_vm<8>();
  comp(bA); epi(0, dotf(bA));
  pref(bA,ab2); s_wait_vm<8>();
  comp(bB); epi(1, dotf(bB));
  pref(bB,ab3); s_wait_vm<8>();
  comp(bA); epi(2, dotf(bA));
  s_wait_vm<0>();
  comp(bB); epi(3, dotf(bB));

  if constexpr (EP==EP_CS){
    float c,q;
    c=csA; q=cqA; c+=__shfl_xor(c,16); c+=__shfl_xor(c,32); q+=__shfl_xor(q,16); q+=__shfl_xor(q,32);
    if(quad==0){ atomicAdd(&st0[col0],c); atomicAdd(&st1[col0],q); }
    c=csB; q=cqB; c+=__shfl_xor(c,16); c+=__shfl_xor(c,32); q+=__shfl_xor(q,16); q+=__shfl_xor(q,32);
    if(quad==0){ atomicAdd(&st0[col1],c); atomicAdd(&st1[col1],q); }
  }
  if constexpr (TRS){
    float c;
    c=csA; c+=__shfl_xor(c,16); c+=__shfl_xor(c,32);
    if(quad==0) atomicAdd(&st0[col0],c);
    c=csB; c+=__shfl_xor(c,16); c+=__shfl_xor(c,32);
    if(quad==0) atomicAdd(&st0[col1],c);
    // transposed store: each wave reads only its own Ts writes (same-wave ds ordering)
    int gn=m0+lane;
    if(gn<NN){
      #pragma unroll
      for(int dd=0;dd<32;dd++) outb[(size_t)(wb+dd)*NN+gn]=Ts[lane][wb+dd];
    }
  }
}

// ---------------- output head: fused bn1+relu+residual+combine then GEMM N=128 ----------------
__global__ __launch_bounds__(512,2)
void k_out(const u16* __restrict__ y2, const u16* __restrict__ x1b, const u16* __restrict__ g0b,
           const u16* __restrict__ WT, const float* __restrict__ bias,
           const float* __restrict__ sc, const float* __restrict__ sh,
           float* __restrict__ outf)
{
  const int tid=threadIdx.x;
  const int wave=tid>>6, lane=tid&63, quad=lane>>4, l15=lane&15;
  const int m0=blockIdx.x*64;
  const int colg=wave*16+l15;              // 8 waves x 16 cols = 128
  __shared__ float scs[DD], shs[DD];
  if(tid<DD){ scs[tid]=sc[tid]; shs[tid]=sh[tid]; }
  __syncthreads();

  u32x4 bf[8];
  { const u16* bp=&WT[(size_t)colg*DD+quad*8];
    #pragma unroll
    for(int ks=0;ks<8;ks++) bf[ks]=*(const u32x4*)(bp+ks*32); }
  float bv=bias[colg];

  #pragma unroll
  for(int mi=0;mi<4;mi++){
    int gr0=m0+mi*16+l15; if(gr0>=NN) gr0=NN-1;
    size_t rb=(size_t)gr0*DD+(size_t)(quad*8);
    u32x4 Y[8],X[8],G[8];
    #pragma unroll
    for(int ks=0;ks<8;ks++) Y[ks]=gld(&y2[rb+ks*32]);
    #pragma unroll
    for(int ks=0;ks<8;ks++) X[ks]=gld(&x1b[rb+ks*32]);
    #pragma unroll
    for(int ks=0;ks<8;ks++) G[ks]=gld(&g0b[rb+ks*32]);
    s_wait_vm<0>();
    f32x4 a={0.f,0.f,0.f,0.f};
    #pragma unroll
    for(int ks=0;ks<8;ks++){
      const u16* py=(const u16*)&Y[ks]; const u16* px=(const u16*)&X[ks]; const u16* pg=(const u16*)&G[ks];
      int k0=ks*32+quad*8;
      u32 w[4];
      #pragma unroll
      for(int j=0;j<4;j++){
        float f0=fmaxf(scs[k0+2*j  ]*b2f(py[2*j  ])+shs[k0+2*j  ],0.f)+b2f(pg[2*j  ]);
        float f1=fmaxf(scs[k0+2*j+1]*b2f(py[2*j+1])+shs[k0+2*j+1],0.f)+b2f(pg[2*j+1]);
        f0=0.8f*f0+0.2f*b2f(px[2*j  ]);
        f1=0.8f*f1+0.2f*b2f(px[2*j+1]);
        w[j]=pack2(f0,f1);
      }
      u32x4 af; af.x=w[0]; af.y=w[1]; af.z=w[2]; af.w=w[3];
      a=mfma16(af,bf[ks],a);
    }
    #pragma unroll
    for(int r=0;r<4;r++){
      int gr=m0+mi*16+quad*4+r;
      if(gr<NN) outf[(size_t)gr*DOUT+colg]=a[r]+bv;
    }
  }
}

// ---------------- launch ----------------
extern "C" void kernel_launch(void* const* d_in, const int* in_sizes, int n_in,
                              void* d_out, int out_size, void* d_ws, size_t ws_size,
                              hipStream_t stream) {
  (void)in_sizes; (void)n_in; (void)out_size; (void)ws_size;
  const float* x     = (const float*)d_in[0];
  const int*   ei    = (const int*)d_in[1];
  const float* tW0   = (const float*)d_in[2];
  const float* tb0   = (const float*)d_in[3];
  const float* tln0g = (const float*)d_in[4];
  const float* tln0b = (const float*)d_in[5];
  const float* Wq    = (const float*)d_in[6];
  const float* bq    = (const float*)d_in[7];
  const float* Wk    = (const float*)d_in[8];
  const float* bk    = (const float*)d_in[9];
  const float* Wv    = (const float*)d_in[10];
  const float* bvv   = (const float*)d_in[11];
  const float* tln1g = (const float*)d_in[12];
  const float* tln1b = (const float*)d_in[13];
  const float* gW0   = (const float*)d_in[14];
  const float* gb0   = (const float*)d_in[15];
  const float* gbn0g = (const float*)d_in[16];
  const float* gbn0b = (const float*)d_in[17];
  const float* gWc   = (const float*)d_in[18];
  const float* gbc   = (const float*)d_in[19];
  const float* gbn1g = (const float*)d_in[20];
  const float* gbn1b = (const float*)d_in[21];
  const float* Wo    = (const float*)d_in[22];
  const float* bo    = (const float*)d_in[23];

  char* ws = (char*)d_ws;
  size_t off = 0;
  auto give = [&](size_t b){ size_t o = off; off += (b + 511) & ~(size_t)511; return o; };
  const size_t NB = (size_t)NN*DD*2;   // 51.2 MB bf16 buffer
  size_t o_b0=give(NB), o_b1=give(NB), o_b2=give(NB), o_b3=give(NB), o_b4=give(NB);
  size_t o_csr = give((size_t)NEG*4);
  size_t o_rowstart = give((NN+1)*4);
  size_t o_cursor   = give(NN*4);
  size_t o_dsq      = give(NN*4);
  size_t o_part     = give(512*4);
  size_t o_wt0=give(DD*DD*2), o_wq=give(DD*DD*2), o_wk=give(DD*DD*2), o_wv=give(DD*DD*2);
  size_t o_wg0=give(DD*DD*2), o_wgc=give(DD*DD*2), o_wo=give(DD*DOUT*2);
  size_t o_kvsT=give(DD*DD*2);
  size_t o_sc0=give(DD*4), o_sh0=give(DD*4), o_sc1=give(DD*4), o_sh1=give(DD*4);
  // zero region (contiguous): deg, kvs, ksum, vsum, cs0, cq0, cs1, cq1
  size_t o_zero = off;
  size_t o_deg = give(NN*4);
  size_t o_kvs = give(DD*DD*4);
  size_t o_ksum=give(DD*4), o_vsum=give(DD*4);
  size_t o_cs0=give(DD*4), o_cq0=give(DD*4), o_cs1=give(DD*4), o_cq1=give(DD*4);
  size_t zero_len = off - o_zero;

  u16* B0=(u16*)(ws+o_b0); u16* B1=(u16*)(ws+o_b1); u16* B2=(u16*)(ws+o_b2);
  u16* B3=(u16*)(ws+o_b3); u16* B4=(u16*)(ws+o_b4);
  int* csr=(int*)(ws+o_csr); int* rowstart=(int*)(ws+o_rowstart); int* cursor=(int*)(ws+o_cursor);
  float* dsq=(float*)(ws+o_dsq); int* part=(int*)(ws+o_part);
  u16* wt0=(u16*)(ws+o_wt0); u16* wq=(u16*)(ws+o_wq); u16* wk=(u16*)(ws+o_wk); u16* wv=(u16*)(ws+o_wv);
  u16* wg0=(u16*)(ws+o_wg0); u16* wgc=(u16*)(ws+o_wgc); u16* wo=(u16*)(ws+o_wo);
  u16* kvsT=(u16*)(ws+o_kvsT);
  float* sc0=(float*)(ws+o_sc0); float* sh0=(float*)(ws+o_sh0);
  float* sc1=(float*)(ws+o_sc1); float* sh1=(float*)(ws+o_sh1);
  int* deg=(int*)(ws+o_deg); float* kvs=(float*)(ws+o_kvs);
  float* ksum=(float*)(ws+o_ksum); float* vsum=(float*)(ws+o_vsum);
  float* cs0=(float*)(ws+o_cs0); float* cq0=(float*)(ws+o_cq0);
  float* cs1=(float*)(ws+o_cs1); float* cq1=(float*)(ws+o_cq1);

  hipMemsetAsync(ws + o_zero, 0, zero_len, stream);

  // weights -> transposed bf16
  k_wtrans<<<256,256,0,stream>>>(tW0, wt0, 256);
  k_wtrans<<<256,256,0,stream>>>(Wq,  wq,  256);
  k_wtrans<<<256,256,0,stream>>>(Wk,  wk,  256);
  k_wtrans<<<256,256,0,stream>>>(Wv,  wv,  256);
  k_wtrans<<<256,256,0,stream>>>(gW0, wg0, 256);
  k_wtrans<<<256,256,0,stream>>>(gWc, wgc, 256);
  k_wtrans<<<128,256,0,stream>>>(Wo,  wo,  128);

  // graph CSR
  k_deg<<<6250,256,0,stream>>>(ei, deg);
  k_scan_a<<<391,256,0,stream>>>(deg, part);
  k_scan_b<<<1,512,0,stream>>>(part);
  k_scan_c<<<391,256,0,stream>>>(deg, part, rowstart, cursor, dsq);
  k_csr<<<6250,256,0,stream>>>(ei, cursor, csr);

  // x -> bf16 (stashed in B2; dead once LN+CS consumed it, then B2 becomes q)
  k_f2bv<<<12500,256,0,stream>>>(x, B2);

  const int MG = 1563;  // ceil(100000/64)
  // h = relu(LN(x@tW0+tb0))
  k_rg<EP_LN><<<MG,512,0,stream>>>(B2, wt0, tb0, B0,
      tln0g, tln0b, nullptr, nullptr, nullptr, nullptr, nullptr);
  // yg = x@gW0+gb0 (+colstats)
  k_rg<EP_CS><<<MG,512,0,stream>>>(B2, wg0, gb0, B1,
      nullptr, nullptr, nullptr, nullptr, nullptr, cs0, cq0);
  // q = rownorm(h@Wq+bq)  (B2 = xb dead -> reuse as q)
  k_rg<EP_QN><<<MG,512,0,stream>>>(B0, wq, bq, B2,
      nullptr, nullptr, nullptr, nullptr, nullptr, nullptr, nullptr);
  // kT = rownorm(h@Wk+bk)^T  (+ksum)
  k_rg<EP_KT><<<MG,512,0,stream>>>(B0, wk, bk, B3,
      nullptr, nullptr, nullptr, nullptr, nullptr, ksum, nullptr);
  // vT = (h@Wv+bv)^T  (+vsum)
  k_rg<EP_VT><<<MG,512,0,stream>>>(B0, wv, bvv, B4,
      nullptr, nullptr, nullptr, nullptr, nullptr, vsum, nullptr);
  // kvs = k^T @ v  (split-K atomic fp32) — legacy engine
  k_gemm<EP_KV,false,256><<<dim3(4,98),256,0,stream>>>(B3, B4, nullptr, nullptr, kvs,
      32, NN, NN, NN, 256);
  k_wtrans<<<256,256,0,stream>>>(kvs, kvsT, 256);
  // BN0 -> g0
  k_bnprep<<<1,256,0,stream>>>(cs0, cq0, gbn0g, gbn0b, sc0, sh0);
  k_bnrelu<<<12500,256,0,stream>>>(B1, sc0, sh0, B3 /*reuse: g0 (kT consumed)*/);
  k_gather<<<12500,256,0,stream>>>(B3, rowstart, csr, dsq, B1 /*agg (yg dead)*/);
  // y2 = agg@gWc+gbc (+colstats)
  k_rg<EP_CS><<<MG,512,0,stream>>>(B1, wgc, gbc, B4 /*y2 (vT dead)*/,
      nullptr, nullptr, nullptr, nullptr, nullptr, cs1, cq1);
  k_bnprep<<<1,256,0,stream>>>(cs1, cq1, gbn1g, gbn1b, sc1, sh1);
  // x1 = relu(LN(( (q@kvs + nf*vsum)/(q@ksum+2nf) + h)/2))
  k_rg<EP_AT><<<MG,512,0,stream>>>(B2, kvsT, nullptr, B1 /*x1 (agg dead)*/,
      tln1g, tln1b, ksum, vsum, B0 /*h*/, nullptr, nullptr);
  // out = (0.8*(relu(bn1(y2))+g0) + 0.2*x1) @ Wo + bo
  k_out<<<MG,512,0,stream>>>(B4 /*y2*/, B1 /*x1*/, B3 /*g0*/, wo, bo, sc1, sh1, (float*)d_out);
}

// Round 3
// 1041.274 us; speedup vs baseline: 1.4966x; 1.4966x over previous
//
#include <hip/hip_runtime.h>
#include <hip/hip_bf16.h>

#define NN 100000
#define NEG 1600000
#define DD 256
#define DOUT 128
#define NTILES 3125   // 100000 / 32

typedef unsigned short u16;
typedef unsigned int u32;
typedef __attribute__((ext_vector_type(8))) __bf16 bf16x8;
typedef __attribute__((ext_vector_type(4))) float f32x4;
typedef __attribute__((ext_vector_type(4))) unsigned int u32x4;

__device__ __forceinline__ float b2f(u16 b){ u32 u=((u32)b)<<16; float f; __builtin_memcpy(&f,&u,4); return f; }
__device__ __forceinline__ u16 f2b(float f){ u32 u; __builtin_memcpy(&u,&f,4); u32 r=(u + 0x7FFFu + ((u>>16)&1u))>>16; return (u16)r; }
__device__ __forceinline__ u32 pack2(float a, float b){ return (u32)f2b(a) | ((u32)f2b(b)<<16); }

template<int N>
__device__ __forceinline__ void s_wait_vm(){
  asm volatile("s_waitcnt vmcnt(%0)" :: "n"(N) : "memory");
  __builtin_amdgcn_sched_barrier(0);
}
__device__ __forceinline__ void tile_barrier(){
  __builtin_amdgcn_s_barrier();
  __builtin_amdgcn_sched_barrier(0);
}
__device__ __forceinline__ void wave_barrier(){
  asm volatile("s_waitcnt lgkmcnt(0)" ::: "memory");
  __builtin_amdgcn_sched_barrier(0);
  __builtin_amdgcn_s_barrier();
  __builtin_amdgcn_sched_barrier(0);
}
__device__ __forceinline__ f32x4 mfma16(u32x4 a, u32x4 b, f32x4 c){
  return __builtin_amdgcn_mfma_f32_16x16x32_bf16(
    __builtin_bit_cast(bf16x8,a), __builtin_bit_cast(bf16x8,b), c, 0,0,0);
}

// ---------------- weight transpose (fp32 [256][ncols] -> bf16 [ncols][256]) ----------------
__global__ void k_wtrans(const float* __restrict__ W, u16* __restrict__ WT, int ncols){
  int n = blockIdx.x; int k = threadIdx.x;
  WT[n*DD + k] = f2b(W[k*ncols + n]);
}

// ---------------- fp32 -> bf16 bulk convert (x) ----------------
__global__ void k_f2bv(const float* __restrict__ in, u16* __restrict__ out){
  long long i = (long long)(blockIdx.x*256 + threadIdx.x) * 8;
  if(i >= (long long)NN*DD) return;
  float4 a = *(const float4*)&in[i];
  float4 b = *(const float4*)&in[i+4];
  uint4 sv;
  sv.x = pack2(a.x,a.y); sv.y = pack2(a.z,a.w);
  sv.z = pack2(b.x,b.y); sv.w = pack2(b.z,b.w);
  *(uint4*)&out[i] = sv;
}

// ---------------- graph prep ----------------
__global__ void k_deg(const int* __restrict__ ei, int* __restrict__ deg){
  int e = blockIdx.x*256 + threadIdx.x;
  if(e < NEG) atomicAdd(&deg[ei[NEG + e]], 1);
}

__global__ void k_scan_a(const int* __restrict__ deg, int* __restrict__ part){
  __shared__ int s[256];
  int i = blockIdx.x*256 + threadIdx.x;
  int v = (i < NN) ? deg[i] : 0;
  s[threadIdx.x] = v; __syncthreads();
  for(int o=128;o>0;o>>=1){ if(threadIdx.x<o) s[threadIdx.x]+=s[threadIdx.x+o]; __syncthreads(); }
  if(threadIdx.x==0) part[blockIdx.x]=s[0];
}

__global__ void k_scan_b(int* __restrict__ part){
  __shared__ int s[512];
  int tx = threadIdx.x;
  int v = (tx < 391) ? part[tx] : 0;
  s[tx] = v; __syncthreads();
  for(int o=1;o<512;o<<=1){ int t=(tx>=o)?s[tx-o]:0; __syncthreads(); s[tx]+=t; __syncthreads(); }
  if(tx < 391) part[tx] = s[tx]-v;  // exclusive
}

__global__ void k_scan_c(const int* __restrict__ deg, const int* __restrict__ part,
                         int* __restrict__ rowstart, int* __restrict__ cursor, float* __restrict__ dsq){
  __shared__ int s[256];
  int tx = threadIdx.x;
  int i = blockIdx.x*256 + tx;
  int v = (i < NN) ? deg[i] : 0;
  s[tx]=v; __syncthreads();
  for(int o=1;o<256;o<<=1){ int t=(tx>=o)?s[tx-o]:0; __syncthreads(); s[tx]+=t; __syncthreads(); }
  int incl = s[tx];
  int base = part[blockIdx.x];
  if(i < NN){
    int excl = base + incl - v;
    rowstart[i]=excl; cursor[i]=excl;
    dsq[i] = (v>0) ? rsqrtf((float)v) : 0.f;
    if(i == NN-1) rowstart[NN] = base + incl;
  }
}

__global__ void k_csr(const int* __restrict__ ei, int* __restrict__ cursor, int* __restrict__ csr_row){
  int e = blockIdx.x*256 + threadIdx.x;
  if(e < NEG){
    int r = ei[e], c = ei[NEG + e];
    int p = atomicAdd(&cursor[c], 1);
    csr_row[p] = r;
  }
}

// ---------------- BN helpers ----------------
__global__ void k_bnprep(const float* __restrict__ cs, const float* __restrict__ cq,
                         const float* __restrict__ g, const float* __restrict__ b,
                         float* __restrict__ scale, float* __restrict__ shift){
  int c = threadIdx.x;
  float m = cs[c] * (1.0f/NN);
  float var = cq[c] * (1.0f/NN) - m*m;
  float rs = rsqrtf(var + 1e-5f);
  float sc = g[c]*rs;
  scale[c] = sc; shift[c] = b[c] - m*sc;
}

__global__ void k_bnrelu(const u16* __restrict__ yg, const float* __restrict__ scale,
                         const float* __restrict__ shift, u16* __restrict__ g0){
  long long i = (long long)(blockIdx.x*256 + threadIdx.x) * 8;
  if(i >= (long long)NN*DD) return;
  int c0 = (int)(i & 255);
  uint4 v = *(const uint4*)&yg[i];
  const u16* p = (const u16*)&v;
  u32 w[4];
  #pragma unroll
  for(int j=0;j<4;j++){
    float a = fmaxf(b2f(p[2*j  ])*scale[c0+2*j  ]+shift[c0+2*j  ], 0.f);
    float b_ = fmaxf(b2f(p[2*j+1])*scale[c0+2*j+1]+shift[c0+2*j+1], 0.f);
    w[j] = pack2(a,b_);
  }
  uint4 sv; sv.x=w[0]; sv.y=w[1]; sv.z=w[2]; sv.w=w[3];
  *(uint4*)&g0[i] = sv;
}

// ---------------- CSR gather ----------------
__global__ __launch_bounds__(256) void k_gather(const u16* __restrict__ g0, const int* __restrict__ rowstart,
                                                const int* __restrict__ csr_row, const float* __restrict__ dsq,
                                                u16* __restrict__ agg){
  int node = blockIdx.x*8 + (threadIdx.x>>5);
  int lane = threadIdx.x & 31;
  if(node >= NN) return;
  int s = rowstart[node], e = rowstart[node+1];
  float di = dsq[node];
  int d0 = lane*8;
  float acc[8] = {0,0,0,0,0,0,0,0};
  int j = s;
  for(; j+1 < e; j += 2){
    int r0 = csr_row[j], r1 = csr_row[j+1];
    float w0 = di*dsq[r0], w1 = di*dsq[r1];
    uint4 a = *(const uint4*)&g0[(size_t)r0*DD + d0];
    uint4 b = *(const uint4*)&g0[(size_t)r1*DD + d0];
    const u16* pa = (const u16*)&a; const u16* pb = (const u16*)&b;
    #pragma unroll
    for(int t=0;t<8;t++){ acc[t] += w0*b2f(pa[t]); acc[t] += w1*b2f(pb[t]); }
  }
  if(j < e){
    int r0 = csr_row[j]; float w0 = di*dsq[r0];
    uint4 a = *(const uint4*)&g0[(size_t)r0*DD + d0];
    const u16* pa = (const u16*)&a;
    #pragma unroll
    for(int t=0;t<8;t++) acc[t] += w0*b2f(pa[t]);
  }
  u32 w[4];
  #pragma unroll
  for(int t=0;t<4;t++) w[t] = pack2(acc[2*t], acc[2*t+1]);
  uint4 sv; sv.x=w[0]; sv.y=w[1]; sv.z=w[2]; sv.w=w[3];
  *(uint4*)&agg[(size_t)node*DD + d0] = sv;
}

enum { EP_LN=0, EP_QN=1, EP_KT=2, EP_VT=3, EP_CS=4, EP_AT=5, EP_OUTP=6, EP_KV=7 };

// ---------------- legacy LDS-staged GEMM (kept only for EP_KV: K=100000 reduction) ----------------
template<int EP, bool AF32, int NCOLS>
__global__ __launch_bounds__(256,2)
void k_gemm(const void* __restrict__ Ap, const u16* __restrict__ BT,
            const float* __restrict__ bias,
            u16* __restrict__ outb, float* __restrict__ outf,
            int kSteps, int kLimit, int Astride, int Bstride, int Mlim)
{
  constexpr int NT = NCOLS/64;
  const int tid = threadIdx.x;
  const int wave = tid>>6, lane = tid&63, quad = lane>>4, l15 = lane&15;
  const int m0 = blockIdx.x*64;
  const int kBase = blockIdx.y*(kSteps*32);
  const int wb = wave*(NCOLS/4);

  __shared__ __align__(16) u16 As[64][48];
  __shared__ __align__(16) u16 Bs[NCOLS][48];

  f32x4 acc[4][NT];
  #pragma unroll
  for(int i=0;i<4;i++)
    #pragma unroll
    for(int j=0;j<NT;j++){ acc[i][j][0]=0.f; acc[i][j][1]=0.f; acc[i][j][2]=0.f; acc[i][j][3]=0.f; }

  for(int st=0; st<kSteps; st++){
    const int k0 = kBase + st*32;
    __syncthreads();
    {
      const u16* Ab = (const u16*)Ap;
      int row=tid>>2, seg=tid&3, gr=m0+row, gk=k0+seg*8;
      uint4 v = make_uint4(0u,0u,0u,0u);
      if(gr<Mlim && gk<kLimit) v = *(const uint4*)&Ab[(size_t)gr*Astride+gk];
      *(uint4*)&As[row][seg*8] = v;
    }
    #pragma unroll
    for(int it=0; it<NCOLS/64; it++){
      int s=tid+it*256, row=s>>2, seg=s&3, gk=k0+seg*8;
      uint4 v = make_uint4(0u,0u,0u,0u);
      if(gk<kLimit) v = *(const uint4*)&BT[(size_t)row*Bstride+gk];
      *(uint4*)&Bs[row][seg*8] = v;
    }
    __syncthreads();
    uint4 afu[4]; uint4 bfu[NT];
    #pragma unroll
    for(int mi=0;mi<4;mi++) afu[mi] = *(const uint4*)&As[mi*16+l15][quad*8];
    #pragma unroll
    for(int ni=0;ni<NT;ni++) bfu[ni] = *(const uint4*)&Bs[wb+ni*16+l15][quad*8];
    #pragma unroll
    for(int mi=0;mi<4;mi++)
      #pragma unroll
      for(int ni=0;ni<NT;ni++)
        acc[mi][ni] = __builtin_amdgcn_mfma_f32_16x16x32_bf16(
            __builtin_bit_cast(bf16x8, afu[mi]),
            __builtin_bit_cast(bf16x8, bfu[ni]),
            acc[mi][ni], 0,0,0);
  }

  #pragma unroll
  for(int mi=0;mi<4;mi++)
    #pragma unroll
    for(int r=0;r<4;r++){
      int gr = m0 + mi*16 + quad*4 + r;
      if(gr<Mlim){
        #pragma unroll
        for(int ni=0;ni<NT;ni++) atomicAdd(&outf[(size_t)gr*DD + wb+ni*16+l15], acc[mi][ni][r]);
      }
    }
}

// ---------------- tile-streaming GEMM engine ----------------
// Persistent blocks (512 thr = 8 waves), grid-stride over 32-row tiles.
// A tile (32x256 bf16 = 16 KB) staged via global_load_lds into a 2-deep LDS
// double buffer with XOR-swizzled source + swizzled ds_read (T2 + rule #21).
// Counted vmcnt(2) per tile: the 2 newest outstanding = next tile's stage.
// B panel (32 cols x 256 K per wave, 64 VGPRs) is weight-stationary.
// Per-tile epilogues use raw s_barrier (no vmcnt drain ever in the loop).
template<int EP>
__global__ __launch_bounds__(512,2)
void k_ts(const u16* __restrict__ Ab, const u16* __restrict__ BT,
          const float* __restrict__ bias,
          u16* __restrict__ outb, float* __restrict__ outf,
          const float* __restrict__ p0, const float* __restrict__ p1,
          const float* __restrict__ p2, const float* __restrict__ p3,
          const float* __restrict__ p4, const float* __restrict__ p5,
          const u16* __restrict__ hb, const u16* __restrict__ y2b, const u16* __restrict__ g0b,
          float* __restrict__ st0, float* __restrict__ st1)
{
  constexpr bool TRS = (EP==EP_KT||EP==EP_VT);
  constexpr int NCW = (EP==EP_OUTP)?16:32;   // cols per wave
  const int tid = threadIdx.x;
  const int wave = tid>>6, lane = tid&63, quad = lane>>4, l15 = lane&15;
  const int wb = wave*NCW;
  const int col0 = wb+l15, col1 = wb+16+l15;   // col1 unused when NCW==16

  __shared__ __align__(16) u16 As[2][8192];    // 2 x 16 KB
  __shared__ float red[2][2][8][16];
  __shared__ float dls[2][16];
  __shared__ u16 Ts[TRS?32:1][TRS?266:1];      // 266: odd dword stride -> conflict-free col read

  // ---- B panel resident in VGPRs ----
  u32x4 bf0[8], bf1[8];
  {
    const u16* b0p = &BT[(size_t)col0*DD + quad*8];
    #pragma unroll
    for(int ks=0;ks<8;ks++) bf0[ks]=*(const u32x4*)(b0p+ks*32);
    if constexpr (NCW==32){
      const u16* b1p = &BT[(size_t)col1*DD + quad*8];
      #pragma unroll
      for(int ks=0;ks<8;ks++) bf1[ks]=*(const u32x4*)(b1p+ks*32);
    }
  }
  float bv0 = bias? bias[col0]:0.f;
  float bv1 = (NCW==32 && bias)? bias[col1]:0.f;
  float g0c=0.f,g1c=0.f,b0c=0.f,b1c=0.f;
  if constexpr (EP==EP_LN||EP==EP_AT){ g0c=p0[col0]; g1c=p0[col1]; b0c=p1[col0]; b1c=p1[col1]; }
  float vs0=0.f, vs1=0.f, sc1a=0.f, sc1b=0.f, sh1a=0.f, sh1b=0.f;
  if constexpr (EP==EP_AT){
    vs0=p3[col0]; vs1=p3[col1];
    sc1a=p4[col0]; sc1b=p4[col1]; sh1a=p5[col0]; sh1b=p5[col1];
  }

  float csA=0.f,csB=0.f,cqA=0.f,cqB=0.f;   // cross-tile col-stat accumulators

  // ---- staging: global -> LDS DMA, source pre-swizzled so swizzled ds_read is linear data ----
  auto stage = [&](int buf, int t){
    #pragma unroll
    for(int it=0; it<2; it++){
      int c = wave + it*8;                 // 1 KB chunk id, wave-uniform
      int row = 2*c + (lane>>5);
      int colb = (lane&31)*16;
      int srcb = colb ^ ((row&7)<<4);      // involution swizzle
      const char* g = (const char*)Ab + ((size_t)t*32 + row)*512 + srcb;
      u16* lp = &As[buf][c*512];           // wave-uniform LDS base; HW adds lane*16
      __builtin_amdgcn_global_load_lds(
        (const __attribute__((address_space(1))) unsigned int*)g,
        (__attribute__((address_space(3))) unsigned int*)lp, 16, 0, 0);
    }
  };
  const char* lbase = (const char*)&As[0][0];
  auto ldfrag = [&](int buf, int mi, int ks)->u32x4{
    int row = mi*16 + l15;
    int cb = (ks*64 + quad*16) ^ ((row&7)<<4);
    return *(const u32x4*)(lbase + buf*16384 + row*512 + cb);
  };

  int t = blockIdx.x;
  int cur = 0;
  if(t < NTILES) stage(0, t);
  for(; t < NTILES; t += gridDim.x){
    int tn = t + (int)gridDim.x;
    if(tn < NTILES){ stage(cur^1, tn); s_wait_vm<2>(); }
    else           { s_wait_vm<0>(); }
    tile_barrier();                        // As[cur] fully staged for all waves

    #pragma unroll
    for(int mi=0; mi<2; mi++){
      const int slot = mi;
      u32x4 fr[8];
      #pragma unroll
      for(int ks=0;ks<8;ks++) fr[ks]=ldfrag(cur,mi,ks);
      f32x4 a0={0.f,0.f,0.f,0.f}, a1={0.f,0.f,0.f,0.f};
      #pragma unroll
      for(int ks=0;ks<8;ks++){
        a0=mfma16(fr[ks],bf0[ks],a0);
        if constexpr (NCW==32) a1=mfma16(fr[ks],bf1[ks],a1);
      }
      const int rbase = t*32 + mi*16;

      if constexpr (EP==EP_OUTP){
        #pragma unroll
        for(int r=0;r<4;r++){
          int gr = rbase + quad*4 + r;
          outf[(size_t)gr*DOUT + col0] = a0[r] + bv0;
        }
      }
      if constexpr (EP==EP_CS){
        #pragma unroll
        for(int r=0;r<4;r++){
          int gr = rbase + quad*4 + r;
          float v0=a0[r]+bv0, v1=a1[r]+bv1;
          outb[(size_t)gr*DD+col0]=f2b(v0);
          outb[(size_t)gr*DD+col1]=f2b(v1);
          csA+=v0; cqA+=v0*v0; csB+=v1; cqB+=v1*v1;
        }
      }
      if constexpr (EP==EP_VT){
        #pragma unroll
        for(int r=0;r<4;r++){
          int row=quad*4+r;
          float v0=a0[r]+bv0, v1=a1[r]+bv1;
          csA+=v0; csB+=v1;
          Ts[mi*16+row][col0]=f2b(v0);
          Ts[mi*16+row][col1]=f2b(v1);
        }
      }
      if constexpr (EP==EP_QN||EP==EP_KT){
        #pragma unroll
        for(int r=0;r<4;r++){
          float v0=a0[r]+bv0, v1=a1[r]+bv1;
          float s2=v0*v0+v1*v1;
          #pragma unroll
          for(int o=1;o<16;o<<=1) s2+=__shfl_xor(s2,o);
          if(l15==0) red[slot][0][wave][quad*4+r]=s2;
        }
        wave_barrier();
        #pragma unroll
        for(int r=0;r<4;r++){
          int row=quad*4+r, gr=rbase+row;
          float S2=0.f;
          #pragma unroll
          for(int w=0;w<8;w++) S2+=red[slot][0][w][row];
          float rsr=rsqrtf(S2);
          if constexpr (EP==EP_QN){
            outb[(size_t)gr*DD+col0]=f2b((a0[r]+bv0)*rsr);
            outb[(size_t)gr*DD+col1]=f2b((a1[r]+bv1)*rsr);
          } else {
            float v0=(a0[r]+bv0)*rsr, v1=(a1[r]+bv1)*rsr;
            csA+=v0; csB+=v1;
            Ts[mi*16+row][col0]=f2b(v0);
            Ts[mi*16+row][col1]=f2b(v1);
          }
        }
      }
      if constexpr (EP==EP_AT){
        float dv=0.f;
        #pragma unroll
        for(int ks=0;ks<8;ks++){
          const u16* ax=(const u16*)&fr[ks];
          #pragma unroll
          for(int j=0;j<8;j++) dv += b2f(ax[j]) * p2[ks*32+quad*8+j];
        }
        dv += __shfl_xor(dv,16); dv += __shfl_xor(dv,32);
        if(wave==0 && quad==0) dls[slot][l15]=dv+200000.0f;   // + 2*nf
        wave_barrier();
        float vv0[4], vv1[4];
        #pragma unroll
        for(int r=0;r<4;r++){
          int row=quad*4+r, gr=rbase+row;
          float den=dls[slot][row];
          size_t rb=(size_t)gr*DD;
          float hv0=b2f(hb[rb+col0]), hv1=b2f(hb[rb+col1]);
          vv0[r]=((a0[r]+100000.0f*vs0)/den + hv0)*0.5f;
          vv1[r]=((a1[r]+100000.0f*vs1)/den + hv1)*0.5f;
        }
        #pragma unroll
        for(int r=0;r<4;r++){
          float s=vv0[r]+vv1[r], s2=vv0[r]*vv0[r]+vv1[r]*vv1[r];
          #pragma unroll
          for(int o=1;o<16;o<<=1){ s+=__shfl_xor(s,o); s2+=__shfl_xor(s2,o); }
          if(l15==0){ red[slot][0][wave][quad*4+r]=s; red[slot][1][wave][quad*4+r]=s2; }
        }
        wave_barrier();
        #pragma unroll
        for(int r=0;r<4;r++){
          int row=quad*4+r, gr=rbase+row;
          float S=0.f,S2=0.f;
          #pragma unroll
          for(int w=0;w<8;w++){ S+=red[slot][0][w][row]; S2+=red[slot][1][w][row]; }
          float mean=S*(1.0f/DD), var=S2*(1.0f/DD)-mean*mean, rstd=rsqrtf(var+1e-5f);
          float x10=fmaxf((vv0[r]-mean)*rstd*g0c+b0c, 0.f);
          float x11=fmaxf((vv1[r]-mean)*rstd*g1c+b1c, 0.f);
          // fuse: comb = 0.8*(relu(bn1(y2))+g0) + 0.2*x1
          size_t rb=(size_t)gr*DD;
          float x20=fmaxf(sc1a*b2f(y2b[rb+col0])+sh1a,0.f)+b2f(g0b[rb+col0]);
          float x21=fmaxf(sc1b*b2f(y2b[rb+col1])+sh1b,0.f)+b2f(g0b[rb+col1]);
          outb[rb+col0]=f2b(0.8f*x20+0.2f*x10);
          outb[rb+col1]=f2b(0.8f*x21+0.2f*x11);
        }
      }
      if constexpr (EP==EP_LN){
        #pragma unroll
        for(int r=0;r<4;r++){
          float v0=a0[r]+bv0, v1=a1[r]+bv1;
          float s=v0+v1, s2=v0*v0+v1*v1;
          #pragma unroll
          for(int o=1;o<16;o<<=1){ s+=__shfl_xor(s,o); s2+=__shfl_xor(s2,o); }
          if(l15==0){ red[slot][0][wave][quad*4+r]=s; red[slot][1][wave][quad*4+r]=s2; }
        }
        wave_barrier();
        #pragma unroll
        for(int r=0;r<4;r++){
          int row=quad*4+r, gr=rbase+row;
          float S=0.f,S2=0.f;
          #pragma unroll
          for(int w=0;w<8;w++){ S+=red[slot][0][w][row]; S2+=red[slot][1][w][row]; }
          float mean=S*(1.0f/DD), var=S2*(1.0f/DD)-mean*mean, rstd=rsqrtf(var+1e-5f);
          float v0=(a0[r]+bv0-mean)*rstd*g0c+b0c;
          float v1=(a1[r]+bv1-mean)*rstd*g1c+b1c;
          outb[(size_t)gr*DD+col0]=f2b(fmaxf(v0,0.f));
          outb[(size_t)gr*DD+col1]=f2b(fmaxf(v1,0.f));
        }
      }
    }

    if constexpr (TRS){
      wave_barrier();                      // all Ts writes visible
      int gcol = t*32 + (lane&31);
      int dbv = wb + (lane>>5)*16;
      #pragma unroll
      for(int dd=0;dd<16;dd++)
        outb[(size_t)(dbv+dd)*NN + gcol] = Ts[lane&31][dbv+dd];
    }

    wave_barrier();                        // all reads of As[cur] (and Ts) done
    cur ^= 1;
  }

  if constexpr (EP==EP_CS){
    float c,q;
    c=csA; q=cqA; c+=__shfl_xor(c,16); c+=__shfl_xor(c,32); q+=__shfl_xor(q,16); q+=__shfl_xor(q,32);
    if(quad==0){ atomicAdd(&st0[col0],c); atomicAdd(&st1[col0],q); }
    c=csB; q=cqB; c+=__shfl_xor(c,16); c+=__shfl_xor(c,32); q+=__shfl_xor(q,16); q+=__shfl_xor(q,32);
    if(quad==0){ atomicAdd(&st0[col1],c); atomicAdd(&st1[col1],q); }
  }
  if constexpr (TRS){
    float c;
    c=csA; c+=__shfl_xor(c,16); c+=__shfl_xor(c,32);
    if(quad==0) atomicAdd(&st0[col0],c);
    c=csB; c+=__shfl_xor(c,16); c+=__shfl_xor(c,32);
    if(quad==0) atomicAdd(&st0[col1],c);
  }
}

// ---------------- launch ----------------
extern "C" void kernel_launch(void* const* d_in, const int* in_sizes, int n_in,
                              void* d_out, int out_size, void* d_ws, size_t ws_size,
                              hipStream_t stream) {
  (void)in_sizes; (void)n_in; (void)out_size; (void)ws_size;
  const float* x     = (const float*)d_in[0];
  const int*   ei    = (const int*)d_in[1];
  const float* tW0   = (const float*)d_in[2];
  const float* tb0   = (const float*)d_in[3];
  const float* tln0g = (const float*)d_in[4];
  const float* tln0b = (const float*)d_in[5];
  const float* Wq    = (const float*)d_in[6];
  const float* bq    = (const float*)d_in[7];
  const float* Wk    = (const float*)d_in[8];
  const float* bk    = (const float*)d_in[9];
  const float* Wv    = (const float*)d_in[10];
  const float* bvv   = (const float*)d_in[11];
  const float* tln1g = (const float*)d_in[12];
  const float* tln1b = (const float*)d_in[13];
  const float* gW0   = (const float*)d_in[14];
  const float* gb0   = (const float*)d_in[15];
  const float* gbn0g = (const float*)d_in[16];
  const float* gbn0b = (const float*)d_in[17];
  const float* gWc   = (const float*)d_in[18];
  const float* gbc   = (const float*)d_in[19];
  const float* gbn1g = (const float*)d_in[20];
  const float* gbn1b = (const float*)d_in[21];
  const float* Wo    = (const float*)d_in[22];
  const float* bo    = (const float*)d_in[23];

  char* ws = (char*)d_ws;
  size_t off = 0;
  auto give = [&](size_t b){ size_t o = off; off += (b + 511) & ~(size_t)511; return o; };
  const size_t NB = (size_t)NN*DD*2;   // 51.2 MB bf16 buffer
  size_t o_b0=give(NB), o_b1=give(NB), o_b2=give(NB), o_b3=give(NB), o_b4=give(NB);
  size_t o_csr = give((size_t)NEG*4);
  size_t o_rowstart = give((NN+1)*4);
  size_t o_cursor   = give(NN*4);
  size_t o_dsq      = give(NN*4);
  size_t o_part     = give(512*4);
  size_t o_wt0=give(DD*DD*2), o_wq=give(DD*DD*2), o_wk=give(DD*DD*2), o_wv=give(DD*DD*2);
  size_t o_wg0=give(DD*DD*2), o_wgc=give(DD*DD*2), o_wo=give(DD*DOUT*2);
  size_t o_kvsT=give(DD*DD*2);
  size_t o_sc0=give(DD*4), o_sh0=give(DD*4), o_sc1=give(DD*4), o_sh1=give(DD*4);
  // zero region (contiguous): deg, kvs, ksum, vsum, cs0, cq0, cs1, cq1
  size_t o_zero = off;
  size_t o_deg = give(NN*4);
  size_t o_kvs = give(DD*DD*4);
  size_t o_ksum=give(DD*4), o_vsum=give(DD*4);
  size_t o_cs0=give(DD*4), o_cq0=give(DD*4), o_cs1=give(DD*4), o_cq1=give(DD*4);
  size_t zero_len = off - o_zero;

  u16* B0=(u16*)(ws+o_b0); u16* B1=(u16*)(ws+o_b1); u16* B2=(u16*)(ws+o_b2);
  u16* B3=(u16*)(ws+o_b3); u16* B4=(u16*)(ws+o_b4);
  int* csr=(int*)(ws+o_csr); int* rowstart=(int*)(ws+o_rowstart); int* cursor=(int*)(ws+o_cursor);
  float* dsq=(float*)(ws+o_dsq); int* part=(int*)(ws+o_part);
  u16* wt0=(u16*)(ws+o_wt0); u16* wq=(u16*)(ws+o_wq); u16* wk=(u16*)(ws+o_wk); u16* wv=(u16*)(ws+o_wv);
  u16* wg0=(u16*)(ws+o_wg0); u16* wgc=(u16*)(ws+o_wgc); u16* wo=(u16*)(ws+o_wo);
  u16* kvsT=(u16*)(ws+o_kvsT);
  float* sc0=(float*)(ws+o_sc0); float* sh0=(float*)(ws+o_sh0);
  float* sc1=(float*)(ws+o_sc1); float* sh1=(float*)(ws+o_sh1);
  int* deg=(int*)(ws+o_deg); float* kvs=(float*)(ws+o_kvs);
  float* ksum=(float*)(ws+o_ksum); float* vsum=(float*)(ws+o_vsum);
  float* cs0=(float*)(ws+o_cs0); float* cq0=(float*)(ws+o_cq0);
  float* cs1=(float*)(ws+o_cs1); float* cq1=(float*)(ws+o_cq1);

  hipMemsetAsync(ws + o_zero, 0, zero_len, stream);

  // weights -> transposed bf16
  k_wtrans<<<256,256,0,stream>>>(tW0, wt0, 256);
  k_wtrans<<<256,256,0,stream>>>(Wq,  wq,  256);
  k_wtrans<<<256,256,0,stream>>>(Wk,  wk,  256);
  k_wtrans<<<256,256,0,stream>>>(Wv,  wv,  256);
  k_wtrans<<<256,256,0,stream>>>(gW0, wg0, 256);
  k_wtrans<<<256,256,0,stream>>>(gWc, wgc, 256);
  k_wtrans<<<128,256,0,stream>>>(Wo,  wo,  128);

  // graph CSR
  k_deg<<<6250,256,0,stream>>>(ei, deg);
  k_scan_a<<<391,256,0,stream>>>(deg, part);
  k_scan_b<<<1,512,0,stream>>>(part);
  k_scan_c<<<391,256,0,stream>>>(deg, part, rowstart, cursor, dsq);
  k_csr<<<6250,256,0,stream>>>(ei, cursor, csr);

  // x -> bf16 (stashed in B2; dead once LN+CS consumed it, then B2 becomes q)
  k_f2bv<<<12500,256,0,stream>>>(x, B2);

  const int TG = 512;   // persistent grid for k_ts
  // h = relu(LN(x@tW0+tb0))
  k_ts<EP_LN><<<TG,512,0,stream>>>(B2, wt0, tb0, B0, nullptr,
      tln0g, tln0b, nullptr, nullptr, nullptr, nullptr,
      nullptr, nullptr, nullptr, nullptr, nullptr);
  // yg = x@gW0+gb0 (+colstats)
  k_ts<EP_CS><<<TG,512,0,stream>>>(B2, wg0, gb0, B1, nullptr,
      nullptr, nullptr, nullptr, nullptr, nullptr, nullptr,
      nullptr, nullptr, nullptr, cs0, cq0);
  // q = rownorm(h@Wq+bq)  (B2 = xb dead -> reuse as q)
  k_ts<EP_QN><<<TG,512,0,stream>>>(B0, wq, bq, B2, nullptr,
      nullptr, nullptr, nullptr, nullptr, nullptr, nullptr,
      nullptr, nullptr, nullptr, nullptr, nullptr);
  // kT = rownorm(h@Wk+bk)^T  (+ksum)
  k_ts<EP_KT><<<TG,512,0,stream>>>(B0, wk, bk, B3, nullptr,
      nullptr, nullptr, nullptr, nullptr, nullptr, nullptr,
      nullptr, nullptr, nullptr, ksum, nullptr);
  // vT = (h@Wv+bv)^T  (+vsum)
  k_ts<EP_VT><<<TG,512,0,stream>>>(B0, wv, bvv, B4, nullptr,
      nullptr, nullptr, nullptr, nullptr, nullptr, nullptr,
      nullptr, nullptr, nullptr, vsum, nullptr);
  // kvs = k^T @ v  (split-K atomic fp32) — legacy engine
  k_gemm<EP_KV,false,256><<<dim3(4,98),256,0,stream>>>(B3, B4, nullptr, nullptr, kvs,
      32, NN, NN, NN, 256);
  k_wtrans<<<256,256,0,stream>>>(kvs, kvsT, 256);
  // BN0 -> g0
  k_bnprep<<<1,256,0,stream>>>(cs0, cq0, gbn0g, gbn0b, sc0, sh0);
  k_bnrelu<<<12500,256,0,stream>>>(B1, sc0, sh0, B3 /*reuse: g0 (kT consumed)*/);
  k_gather<<<12500,256,0,stream>>>(B3, rowstart, csr, dsq, B1 /*agg (yg dead)*/);
  // y2 = agg@gWc+gbc (+colstats)
  k_ts<EP_CS><<<TG,512,0,stream>>>(B1, wgc, gbc, B4 /*y2 (vT dead)*/, nullptr,
      nullptr, nullptr, nullptr, nullptr, nullptr, nullptr,
      nullptr, nullptr, nullptr, cs1, cq1);
  k_bnprep<<<1,256,0,stream>>>(cs1, cq1, gbn1g, gbn1b, sc1, sh1);
  // comb = 0.8*(relu(bn1(y2))+g0) + 0.2*relu(LN((q@kvs+nf*vsum)/(q@ksum+2nf)+h)/..)
  k_ts<EP_AT><<<TG,512,0,stream>>>(B2, kvsT, nullptr, B1 /*comb (agg dead)*/, nullptr,
      tln1g, tln1b, ksum, vsum, sc1, sh1,
      B0 /*h*/, B4 /*y2*/, B3 /*g0*/, nullptr, nullptr);
  // out = comb @ Wo + bo
  k_ts<EP_OUTP><<<TG,512,0,stream>>>(B1 /*comb*/, wo, bo, nullptr, (float*)d_out,
      nullptr, nullptr, nullptr, nullptr, nullptr, nullptr,
      nullptr, nullptr, nullptr, nullptr, nullptr);
}

// Round 4
// 887.653 us; speedup vs baseline: 1.7556x; 1.1731x over previous
//
#include <hip/hip_runtime.h>
#include <hip/hip_bf16.h>

#define NN 100000
#define NEG 1600000
#define DD 256
#define DOUT 128
#define NTILES 3125   // 100000 / 32
#define NBK 782       // buckets: c>>7, 99999>>7 = 781
#define BCAP 2600     // per-bucket capacity (Poisson mean 2048, +12 sigma margin)

typedef unsigned short u16;
typedef unsigned int u32;
typedef __attribute__((ext_vector_type(8))) __bf16 bf16x8;
typedef __attribute__((ext_vector_type(4))) float f32x4;
typedef __attribute__((ext_vector_type(4))) unsigned int u32x4;

__device__ __forceinline__ float b2f(u16 b){ u32 u=((u32)b)<<16; float f; __builtin_memcpy(&f,&u,4); return f; }
__device__ __forceinline__ u16 f2b(float f){ u32 u; __builtin_memcpy(&u,&f,4); u32 r=(u + 0x7FFFu + ((u>>16)&1u))>>16; return (u16)r; }
__device__ __forceinline__ u32 pack2(float a, float b){ return (u32)f2b(a) | ((u32)f2b(b)<<16); }

template<int N>
__device__ __forceinline__ void s_wait_vm(){
  asm volatile("s_waitcnt vmcnt(%0)" :: "n"(N) : "memory");
  __builtin_amdgcn_sched_barrier(0);
}
__device__ __forceinline__ void tile_barrier(){
  __builtin_amdgcn_s_barrier();
  __builtin_amdgcn_sched_barrier(0);
}
__device__ __forceinline__ void wave_barrier(){
  asm volatile("s_waitcnt lgkmcnt(0)" ::: "memory");
  __builtin_amdgcn_sched_barrier(0);
  __builtin_amdgcn_s_barrier();
  __builtin_amdgcn_sched_barrier(0);
}
__device__ __forceinline__ f32x4 mfma16(u32x4 a, u32x4 b, f32x4 c){
  return __builtin_amdgcn_mfma_f32_16x16x32_bf16(
    __builtin_bit_cast(bf16x8,a), __builtin_bit_cast(bf16x8,b), c, 0,0,0);
}

// ---------------- weight transpose (fp32 [256][ncols] -> bf16 [ncols][256]) ----------------
__global__ void k_wtrans(const float* __restrict__ W, u16* __restrict__ WT, int ncols){
  int n = blockIdx.x; int k = threadIdx.x;
  WT[n*DD + k] = f2b(W[k*ncols + n]);
}

// ---------------- fp32 -> bf16 bulk convert (x) ----------------
__global__ void k_f2bv(const float* __restrict__ in, u16* __restrict__ out){
  long long i = (long long)(blockIdx.x*256 + threadIdx.x) * 8;
  if(i >= (long long)NN*DD) return;
  float4 a = *(const float4*)&in[i];
  float4 b = *(const float4*)&in[i+4];
  uint4 sv;
  sv.x = pack2(a.x,a.y); sv.y = pack2(a.z,a.w);
  sv.z = pack2(b.x,b.y); sv.w = pack2(b.z,b.w);
  *(uint4*)&out[i] = sv;
}

// ---------------- graph prep: 2-level bucket sort -> sequential CSR scatter ----------------
// Pass 1: scatter edges into 782 col-buckets (packed rec = (c&127)<<17 | r).
// Per-block LDS histogram + one window reservation per (block,bucket) keeps
// global atomics ~300K (vs 1.6M) and makes writes window-contiguous.
__global__ __launch_bounds__(256)
void k_bscat(const int* __restrict__ ei, int* __restrict__ gcur, u32* __restrict__ brec){
  __shared__ int hist[NBK];
  __shared__ int wbase[NBK];
  const int tid = threadIdx.x;
  for(int i=tid;i<NBK;i+=256) hist[i]=0;
  __syncthreads();
  const int e0 = blockIdx.x*4096;
  int r[16], c[16];
  #pragma unroll
  for(int i=0;i<16;i++){
    int e = e0 + tid + i*256;
    bool ok = e < NEG;
    r[i] = ok ? ei[e] : -1;
    c[i] = ok ? ei[NEG+e] : 0;
    if(ok) atomicAdd(&hist[c[i]>>7], 1);
  }
  __syncthreads();
  for(int i=tid;i<NBK;i+=256){
    int n = hist[i];
    wbase[i] = (n>0) ? atomicAdd(&gcur[i], n) : 0;
  }
  __syncthreads();
  #pragma unroll
  for(int i=0;i<16;i++){
    if(r[i]>=0){
      int b = c[i]>>7;
      int rk = atomicSub(&hist[b],1) - 1;    // unique in-block rank
      brec[b*BCAP + wbase[b] + rk] = ((u32)(c[i]&127)<<17) | (u32)r[i];
    }
  }
}

// Pass 2: per-bucket node-degree histogram -> coalesced deg writes (replaces random-atomic k_deg)
__global__ __launch_bounds__(256)
void k_bdeg(const u32* __restrict__ brec, const int* __restrict__ gcur, int* __restrict__ deg){
  __shared__ int cnt[128];
  const int b = blockIdx.x, tid = threadIdx.x;
  if(tid<128) cnt[tid]=0;
  __syncthreads();
  const int n = gcur[b];
  for(int i=tid;i<n;i+=256) atomicAdd(&cnt[(brec[b*BCAP+i]>>17)&127], 1);
  __syncthreads();
  int node = b*128 + tid;
  if(tid<128 && node<NN) deg[node] = cnt[tid];
}

// Pass 3: final CSR placement; all of a bucket's writes land in one ~8KB rowstart window
__global__ __launch_bounds__(256)
void k_bcsr(const u32* __restrict__ brec, const int* __restrict__ gcur,
            const int* __restrict__ rowstart, int* __restrict__ csr_row){
  __shared__ int cnt[128];
  __shared__ int base[128];
  const int b = blockIdx.x, tid = threadIdx.x;
  if(tid<128){
    cnt[tid]=0;
    int node = b*128 + tid;
    base[tid] = (node<NN) ? rowstart[node] : 0;
  }
  __syncthreads();
  const int n = gcur[b];
  for(int i=tid;i<n;i+=256){
    u32 rec = brec[b*BCAP+i];
    int lc = (rec>>17)&127;
    int rk = atomicAdd(&cnt[lc],1);
    csr_row[base[lc]+rk] = (int)(rec & 0x1FFFFu);
  }
}

__global__ void k_scan_a(const int* __restrict__ deg, int* __restrict__ part){
  __shared__ int s[256];
  int i = blockIdx.x*256 + threadIdx.x;
  int v = (i < NN) ? deg[i] : 0;
  s[threadIdx.x] = v; __syncthreads();
  for(int o=128;o>0;o>>=1){ if(threadIdx.x<o) s[threadIdx.x]+=s[threadIdx.x+o]; __syncthreads(); }
  if(threadIdx.x==0) part[blockIdx.x]=s[0];
}

__global__ void k_scan_b(int* __restrict__ part){
  __shared__ int s[512];
  int tx = threadIdx.x;
  int v = (tx < 391) ? part[tx] : 0;
  s[tx] = v; __syncthreads();
  for(int o=1;o<512;o<<=1){ int t=(tx>=o)?s[tx-o]:0; __syncthreads(); s[tx]+=t; __syncthreads(); }
  if(tx < 391) part[tx] = s[tx]-v;  // exclusive
}

__global__ void k_scan_c(const int* __restrict__ deg, const int* __restrict__ part,
                         int* __restrict__ rowstart, float* __restrict__ dsq){
  __shared__ int s[256];
  int tx = threadIdx.x;
  int i = blockIdx.x*256 + tx;
  int v = (i < NN) ? deg[i] : 0;
  s[tx]=v; __syncthreads();
  for(int o=1;o<256;o<<=1){ int t=(tx>=o)?s[tx-o]:0; __syncthreads(); s[tx]+=t; __syncthreads(); }
  int incl = s[tx];
  int base = part[blockIdx.x];
  if(i < NN){
    int excl = base + incl - v;
    rowstart[i]=excl;
    dsq[i] = (v>0) ? rsqrtf((float)v) : 0.f;
    if(i == NN-1) rowstart[NN] = base + incl;
  }
}

// ---------------- BN helpers ----------------
__global__ void k_bnprep(const float* __restrict__ cs, const float* __restrict__ cq,
                         const float* __restrict__ g, const float* __restrict__ b,
                         float* __restrict__ scale, float* __restrict__ shift){
  int c = threadIdx.x;
  float m = cs[c] * (1.0f/NN);
  float var = cq[c] * (1.0f/NN) - m*m;
  float rs = rsqrtf(var + 1e-5f);
  float sc = g[c]*rs;
  scale[c] = sc; shift[c] = b[c] - m*sc;
}

__global__ void k_bnrelu(const u16* __restrict__ yg, const float* __restrict__ scale,
                         const float* __restrict__ shift, u16* __restrict__ g0){
  long long i = (long long)(blockIdx.x*256 + threadIdx.x) * 8;
  if(i >= (long long)NN*DD) return;
  int c0 = (int)(i & 255);
  uint4 v = *(const uint4*)&yg[i];
  const u16* p = (const u16*)&v;
  u32 w[4];
  #pragma unroll
  for(int j=0;j<4;j++){
    float a = fmaxf(b2f(p[2*j  ])*scale[c0+2*j  ]+shift[c0+2*j  ], 0.f);
    float b_ = fmaxf(b2f(p[2*j+1])*scale[c0+2*j+1]+shift[c0+2*j+1], 0.f);
    w[j] = pack2(a,b_);
  }
  uint4 sv; sv.x=w[0]; sv.y=w[1]; sv.z=w[2]; sv.w=w[3];
  *(uint4*)&g0[i] = sv;
}

// ---------------- CSR gather ----------------
__global__ __launch_bounds__(256) void k_gather(const u16* __restrict__ g0, const int* __restrict__ rowstart,
                                                const int* __restrict__ csr_row, const float* __restrict__ dsq,
                                                u16* __restrict__ agg){
  int node = blockIdx.x*8 + (threadIdx.x>>5);
  int lane = threadIdx.x & 31;
  if(node >= NN) return;
  int s = rowstart[node], e = rowstart[node+1];
  float di = dsq[node];
  int d0 = lane*8;
  float acc[8] = {0,0,0,0,0,0,0,0};
  int j = s;
  for(; j+1 < e; j += 2){
    int r0 = csr_row[j], r1 = csr_row[j+1];
    float w0 = di*dsq[r0], w1 = di*dsq[r1];
    uint4 a = *(const uint4*)&g0[(size_t)r0*DD + d0];
    uint4 b = *(const uint4*)&g0[(size_t)r1*DD + d0];
    const u16* pa = (const u16*)&a; const u16* pb = (const u16*)&b;
    #pragma unroll
    for(int t=0;t<8;t++){ acc[t] += w0*b2f(pa[t]); acc[t] += w1*b2f(pb[t]); }
  }
  if(j < e){
    int r0 = csr_row[j]; float w0 = di*dsq[r0];
    uint4 a = *(const uint4*)&g0[(size_t)r0*DD + d0];
    const u16* pa = (const u16*)&a;
    #pragma unroll
    for(int t=0;t<8;t++) acc[t] += w0*b2f(pa[t]);
  }
  u32 w[4];
  #pragma unroll
  for(int t=0;t<4;t++) w[t] = pack2(acc[2*t], acc[2*t+1]);
  uint4 sv; sv.x=w[0]; sv.y=w[1]; sv.z=w[2]; sv.w=w[3];
  *(uint4*)&agg[(size_t)node*DD + d0] = sv;
}

enum { EP_LN=0, EP_QN=1, EP_KT=2, EP_VT=3, EP_CS=4, EP_AT=5, EP_OUTP=6, EP_KV=7 };

// ---------------- legacy LDS-staged GEMM (kept only for EP_KV: K=100000 reduction) ----------------
template<int EP, bool AF32, int NCOLS>
__global__ __launch_bounds__(256,2)
void k_gemm(const void* __restrict__ Ap, const u16* __restrict__ BT,
            const float* __restrict__ bias,
            u16* __restrict__ outb, float* __restrict__ outf,
            int kSteps, int kLimit, int Astride, int Bstride, int Mlim)
{
  constexpr int NT = NCOLS/64;
  const int tid = threadIdx.x;
  const int wave = tid>>6, lane = tid&63, quad = lane>>4, l15 = lane&15;
  const int m0 = blockIdx.x*64;
  const int kBase = blockIdx.y*(kSteps*32);
  const int wb = wave*(NCOLS/4);

  __shared__ __align__(16) u16 As[64][48];
  __shared__ __align__(16) u16 Bs[NCOLS][48];

  f32x4 acc[4][NT];
  #pragma unroll
  for(int i=0;i<4;i++)
    #pragma unroll
    for(int j=0;j<NT;j++){ acc[i][j][0]=0.f; acc[i][j][1]=0.f; acc[i][j][2]=0.f; acc[i][j][3]=0.f; }

  for(int st=0; st<kSteps; st++){
    const int k0 = kBase + st*32;
    __syncthreads();
    {
      const u16* Ab = (const u16*)Ap;
      int row=tid>>2, seg=tid&3, gr=m0+row, gk=k0+seg*8;
      uint4 v = make_uint4(0u,0u,0u,0u);
      if(gr<Mlim && gk<kLimit) v = *(const uint4*)&Ab[(size_t)gr*Astride+gk];
      *(uint4*)&As[row][seg*8] = v;
    }
    #pragma unroll
    for(int it=0; it<NCOLS/64; it++){
      int s=tid+it*256, row=s>>2, seg=s&3, gk=k0+seg*8;
      uint4 v = make_uint4(0u,0u,0u,0u);
      if(gk<kLimit) v = *(const uint4*)&BT[(size_t)row*Bstride+gk];
      *(uint4*)&Bs[row][seg*8] = v;
    }
    __syncthreads();
    uint4 afu[4]; uint4 bfu[NT];
    #pragma unroll
    for(int mi=0;mi<4;mi++) afu[mi] = *(const uint4*)&As[mi*16+l15][quad*8];
    #pragma unroll
    for(int ni=0;ni<NT;ni++) bfu[ni] = *(const uint4*)&Bs[wb+ni*16+l15][quad*8];
    #pragma unroll
    for(int mi=0;mi<4;mi++)
      #pragma unroll
      for(int ni=0;ni<NT;ni++)
        acc[mi][ni] = __builtin_amdgcn_mfma_f32_16x16x32_bf16(
            __builtin_bit_cast(bf16x8, afu[mi]),
            __builtin_bit_cast(bf16x8, bfu[ni]),
            acc[mi][ni], 0,0,0);
  }

  #pragma unroll
  for(int mi=0;mi<4;mi++)
    #pragma unroll
    for(int r=0;r<4;r++){
      int gr = m0 + mi*16 + quad*4 + r;
      if(gr<Mlim){
        #pragma unroll
        for(int ni=0;ni<NT;ni++) atomicAdd(&outf[(size_t)gr*DD + wb+ni*16+l15], acc[mi][ni][r]);
      }
    }
}

// ---------------- tile-streaming GEMM engine ----------------
// Persistent blocks (512 thr = 8 waves), grid-stride over 32-row tiles.
// A tile (32x256 bf16 = 16 KB) staged via global_load_lds into a 2-deep LDS
// double buffer with XOR-swizzled source + swizzled ds_read (T2 + rule #21).
// Counted vmcnt(2) per tile: the 2 newest outstanding = next tile's stage.
// B panel (32 cols x 256 K per wave, 64 VGPRs) is weight-stationary.
// Per-tile epilogues use raw s_barrier (no vmcnt drain ever in the loop).
template<int EP>
__global__ __launch_bounds__(512,2)
void k_ts(const u16* __restrict__ Ab, const u16* __restrict__ BT,
          const float* __restrict__ bias,
          u16* __restrict__ outb, float* __restrict__ outf,
          const float* __restrict__ p0, const float* __restrict__ p1,
          const float* __restrict__ p2, const float* __restrict__ p3,
          const float* __restrict__ p4, const float* __restrict__ p5,
          const u16* __restrict__ hb, const u16* __restrict__ y2b, const u16* __restrict__ g0b,
          float* __restrict__ st0, float* __restrict__ st1)
{
  constexpr bool TRS = (EP==EP_KT||EP==EP_VT);
  constexpr int NCW = (EP==EP_OUTP)?16:32;   // cols per wave
  const int tid = threadIdx.x;
  const int wave = tid>>6, lane = tid&63, quad = lane>>4, l15 = lane&15;
  const int wb = wave*NCW;
  const int col0 = wb+l15, col1 = wb+16+l15;   // col1 unused when NCW==16

  __shared__ __align__(16) u16 As[2][8192];    // 2 x 16 KB
  __shared__ float red[2][2][8][16];
  __shared__ float dls[2][16];
  __shared__ u16 Ts[TRS?32:1][TRS?266:1];      // 266: odd dword stride -> conflict-free col read

  // ---- B panel resident in VGPRs ----
  u32x4 bf0[8], bf1[8];
  {
    const u16* b0p = &BT[(size_t)col0*DD + quad*8];
    #pragma unroll
    for(int ks=0;ks<8;ks++) bf0[ks]=*(const u32x4*)(b0p+ks*32);
    if constexpr (NCW==32){
      const u16* b1p = &BT[(size_t)col1*DD + quad*8];
      #pragma unroll
      for(int ks=0;ks<8;ks++) bf1[ks]=*(const u32x4*)(b1p+ks*32);
    }
  }
  float bv0 = bias? bias[col0]:0.f;
  float bv1 = (NCW==32 && bias)? bias[col1]:0.f;
  float g0c=0.f,g1c=0.f,b0c=0.f,b1c=0.f;
  if constexpr (EP==EP_LN||EP==EP_AT){ g0c=p0[col0]; g1c=p0[col1]; b0c=p1[col0]; b1c=p1[col1]; }
  float vs0=0.f, vs1=0.f, sc1a=0.f, sc1b=0.f, sh1a=0.f, sh1b=0.f;
  if constexpr (EP==EP_AT){
    vs0=p3[col0]; vs1=p3[col1];
    sc1a=p4[col0]; sc1b=p4[col1]; sh1a=p5[col0]; sh1b=p5[col1];
  }

  float csA=0.f,csB=0.f,cqA=0.f,cqB=0.f;   // cross-tile col-stat accumulators

  // ---- staging: global -> LDS DMA, source pre-swizzled so swizzled ds_read is linear data ----
  auto stage = [&](int buf, int t){
    #pragma unroll
    for(int it=0; it<2; it++){
      int c = wave + it*8;                 // 1 KB chunk id, wave-uniform
      int row = 2*c + (lane>>5);
      int colb = (lane&31)*16;
      int srcb = colb ^ ((row&7)<<4);      // involution swizzle
      const char* g = (const char*)Ab + ((size_t)t*32 + row)*512 + srcb;
      u16* lp = &As[buf][c*512];           // wave-uniform LDS base; HW adds lane*16
      __builtin_amdgcn_global_load_lds(
        (const __attribute__((address_space(1))) unsigned int*)g,
        (__attribute__((address_space(3))) unsigned int*)lp, 16, 0, 0);
    }
  };
  const char* lbase = (const char*)&As[0][0];
  auto ldfrag = [&](int buf, int mi, int ks)->u32x4{
    int row = mi*16 + l15;
    int cb = (ks*64 + quad*16) ^ ((row&7)<<4);
    return *(const u32x4*)(lbase + buf*16384 + row*512 + cb);
  };

  int t = blockIdx.x;
  int cur = 0;
  if(t < NTILES) stage(0, t);
  for(; t < NTILES; t += gridDim.x){
    int tn = t + (int)gridDim.x;
    if(tn < NTILES){ stage(cur^1, tn); s_wait_vm<2>(); }
    else           { s_wait_vm<0>(); }
    tile_barrier();                        // As[cur] fully staged for all waves

    #pragma unroll
    for(int mi=0; mi<2; mi++){
      const int slot = mi;
      u32x4 fr[8];
      #pragma unroll
      for(int ks=0;ks<8;ks++) fr[ks]=ldfrag(cur,mi,ks);
      f32x4 a0={0.f,0.f,0.f,0.f}, a1={0.f,0.f,0.f,0.f};
      #pragma unroll
      for(int ks=0;ks<8;ks++){
        a0=mfma16(fr[ks],bf0[ks],a0);
        if constexpr (NCW==32) a1=mfma16(fr[ks],bf1[ks],a1);
      }
      const int rbase = t*32 + mi*16;

      if constexpr (EP==EP_OUTP){
        #pragma unroll
        for(int r=0;r<4;r++){
          int gr = rbase + quad*4 + r;
          outf[(size_t)gr*DOUT + col0] = a0[r] + bv0;
        }
      }
      if constexpr (EP==EP_CS){
        #pragma unroll
        for(int r=0;r<4;r++){
          int gr = rbase + quad*4 + r;
          float v0=a0[r]+bv0, v1=a1[r]+bv1;
          outb[(size_t)gr*DD+col0]=f2b(v0);
          outb[(size_t)gr*DD+col1]=f2b(v1);
          csA+=v0; cqA+=v0*v0; csB+=v1; cqB+=v1*v1;
        }
      }
      if constexpr (EP==EP_VT){
        #pragma unroll
        for(int r=0;r<4;r++){
          int row=quad*4+r;
          float v0=a0[r]+bv0, v1=a1[r]+bv1;
          csA+=v0; csB+=v1;
          Ts[mi*16+row][col0]=f2b(v0);
          Ts[mi*16+row][col1]=f2b(v1);
        }
      }
      if constexpr (EP==EP_QN||EP==EP_KT){
        #pragma unroll
        for(int r=0;r<4;r++){
          float v0=a0[r]+bv0, v1=a1[r]+bv1;
          float s2=v0*v0+v1*v1;
          #pragma unroll
          for(int o=1;o<16;o<<=1) s2+=__shfl_xor(s2,o);
          if(l15==0) red[slot][0][wave][quad*4+r]=s2;
        }
        wave_barrier();
        #pragma unroll
        for(int r=0;r<4;r++){
          int row=quad*4+r, gr=rbase+row;
          float S2=0.f;
          #pragma unroll
          for(int w=0;w<8;w++) S2+=red[slot][0][w][row];
          float rsr=rsqrtf(S2);
          if constexpr (EP==EP_QN){
            outb[(size_t)gr*DD+col0]=f2b((a0[r]+bv0)*rsr);
            outb[(size_t)gr*DD+col1]=f2b((a1[r]+bv1)*rsr);
          } else {
            float v0=(a0[r]+bv0)*rsr, v1=(a1[r]+bv1)*rsr;
            csA+=v0; csB+=v1;
            Ts[mi*16+row][col0]=f2b(v0);
            Ts[mi*16+row][col1]=f2b(v1);
          }
        }
      }
      if constexpr (EP==EP_AT){
        float dv=0.f;
        #pragma unroll
        for(int ks=0;ks<8;ks++){
          const u16* ax=(const u16*)&fr[ks];
          #pragma unroll
          for(int j=0;j<8;j++) dv += b2f(ax[j]) * p2[ks*32+quad*8+j];
        }
        dv += __shfl_xor(dv,16); dv += __shfl_xor(dv,32);
        if(wave==0 && quad==0) dls[slot][l15]=dv+200000.0f;   // + 2*nf
        wave_barrier();
        float vv0[4], vv1[4];
        #pragma unroll
        for(int r=0;r<4;r++){
          int row=quad*4+r, gr=rbase+row;
          float den=dls[slot][row];
          size_t rb=(size_t)gr*DD;
          float hv0=b2f(hb[rb+col0]), hv1=b2f(hb[rb+col1]);
          vv0[r]=((a0[r]+100000.0f*vs0)/den + hv0)*0.5f;
          vv1[r]=((a1[r]+100000.0f*vs1)/den + hv1)*0.5f;
        }
        #pragma unroll
        for(int r=0;r<4;r++){
          float s=vv0[r]+vv1[r], s2=vv0[r]*vv0[r]+vv1[r]*vv1[r];
          #pragma unroll
          for(int o=1;o<16;o<<=1){ s+=__shfl_xor(s,o); s2+=__shfl_xor(s2,o); }
          if(l15==0){ red[slot][0][wave][quad*4+r]=s; red[slot][1][wave][quad*4+r]=s2; }
        }
        wave_barrier();
        #pragma unroll
        for(int r=0;r<4;r++){
          int row=quad*4+r, gr=rbase+row;
          float S=0.f,S2=0.f;
          #pragma unroll
          for(int w=0;w<8;w++){ S+=red[slot][0][w][row]; S2+=red[slot][1][w][row]; }
          float mean=S*(1.0f/DD), var=S2*(1.0f/DD)-mean*mean, rstd=rsqrtf(var+1e-5f);
          float x10=fmaxf((vv0[r]-mean)*rstd*g0c+b0c, 0.f);
          float x11=fmaxf((vv1[r]-mean)*rstd*g1c+b1c, 0.f);
          // fuse: comb = 0.8*(relu(bn1(y2))+g0) + 0.2*x1
          size_t rb=(size_t)gr*DD;
          float x20=fmaxf(sc1a*b2f(y2b[rb+col0])+sh1a,0.f)+b2f(g0b[rb+col0]);
          float x21=fmaxf(sc1b*b2f(y2b[rb+col1])+sh1b,0.f)+b2f(g0b[rb+col1]);
          outb[rb+col0]=f2b(0.8f*x20+0.2f*x10);
          outb[rb+col1]=f2b(0.8f*x21+0.2f*x11);
        }
      }
      if constexpr (EP==EP_LN){
        #pragma unroll
        for(int r=0;r<4;r++){
          float v0=a0[r]+bv0, v1=a1[r]+bv1;
          float s=v0+v1, s2=v0*v0+v1*v1;
          #pragma unroll
          for(int o=1;o<16;o<<=1){ s+=__shfl_xor(s,o); s2+=__shfl_xor(s2,o); }
          if(l15==0){ red[slot][0][wave][quad*4+r]=s; red[slot][1][wave][quad*4+r]=s2; }
        }
        wave_barrier();
        #pragma unroll
        for(int r=0;r<4;r++){
          int row=quad*4+r, gr=rbase+row;
          float S=0.f,S2=0.f;
          #pragma unroll
          for(int w=0;w<8;w++){ S+=red[slot][0][w][row]; S2+=red[slot][1][w][row]; }
          float mean=S*(1.0f/DD), var=S2*(1.0f/DD)-mean*mean, rstd=rsqrtf(var+1e-5f);
          float v0=(a0[r]+bv0-mean)*rstd*g0c+b0c;
          float v1=(a1[r]+bv1-mean)*rstd*g1c+b1c;
          outb[(size_t)gr*DD+col0]=f2b(fmaxf(v0,0.f));
          outb[(size_t)gr*DD+col1]=f2b(fmaxf(v1,0.f));
        }
      }
    }

    if constexpr (TRS){
      wave_barrier();                      // all Ts writes visible
      int gcol = t*32 + (lane&31);
      int dbv = wb + (lane>>5)*16;
      #pragma unroll
      for(int dd=0;dd<16;dd++)
        outb[(size_t)(dbv+dd)*NN + gcol] = Ts[lane&31][dbv+dd];
    }

    wave_barrier();                        // all reads of As[cur] (and Ts) done
    cur ^= 1;
  }

  if constexpr (EP==EP_CS){
    float c,q;
    c=csA; q=cqA; c+=__shfl_xor(c,16); c+=__shfl_xor(c,32); q+=__shfl_xor(q,16); q+=__shfl_xor(q,32);
    if(quad==0){ atomicAdd(&st0[col0],c); atomicAdd(&st1[col0],q); }
    c=csB; q=cqB; c+=__shfl_xor(c,16); c+=__shfl_xor(c,32); q+=__shfl_xor(q,16); q+=__shfl_xor(q,32);
    if(quad==0){ atomicAdd(&st0[col1],c); atomicAdd(&st1[col1],q); }
  }
  if constexpr (TRS){
    float c;
    c=csA; c+=__shfl_xor(c,16); c+=__shfl_xor(c,32);
    if(quad==0) atomicAdd(&st0[col0],c);
    c=csB; c+=__shfl_xor(c,16); c+=__shfl_xor(c,32);
    if(quad==0) atomicAdd(&st0[col1],c);
  }
}

// ---------------- launch ----------------
extern "C" void kernel_launch(void* const* d_in, const int* in_sizes, int n_in,
                              void* d_out, int out_size, void* d_ws, size_t ws_size,
                              hipStream_t stream) {
  (void)in_sizes; (void)n_in; (void)out_size; (void)ws_size;
  const float* x     = (const float*)d_in[0];
  const int*   ei    = (const int*)d_in[1];
  const float* tW0   = (const float*)d_in[2];
  const float* tb0   = (const float*)d_in[3];
  const float* tln0g = (const float*)d_in[4];
  const float* tln0b = (const float*)d_in[5];
  const float* Wq    = (const float*)d_in[6];
  const float* bq    = (const float*)d_in[7];
  const float* Wk    = (const float*)d_in[8];
  const float* bk    = (const float*)d_in[9];
  const float* Wv    = (const float*)d_in[10];
  const float* bvv   = (const float*)d_in[11];
  const float* tln1g = (const float*)d_in[12];
  const float* tln1b = (const float*)d_in[13];
  const float* gW0   = (const float*)d_in[14];
  const float* gb0   = (const float*)d_in[15];
  const float* gbn0g = (const float*)d_in[16];
  const float* gbn0b = (const float*)d_in[17];
  const float* gWc   = (const float*)d_in[18];
  const float* gbc   = (const float*)d_in[19];
  const float* gbn1g = (const float*)d_in[20];
  const float* gbn1b = (const float*)d_in[21];
  const float* Wo    = (const float*)d_in[22];
  const float* bo    = (const float*)d_in[23];

  char* ws = (char*)d_ws;
  size_t off = 0;
  auto give = [&](size_t b){ size_t o = off; off += (b + 511) & ~(size_t)511; return o; };
  const size_t NB = (size_t)NN*DD*2;   // 51.2 MB bf16 buffer
  size_t o_b0=give(NB), o_b1=give(NB), o_b2=give(NB), o_b3=give(NB), o_b4=give(NB);
  size_t o_csr = give((size_t)NEG*4);
  size_t o_brec = give((size_t)NBK*BCAP*4);
  size_t o_rowstart = give((NN+1)*4);
  size_t o_dsq      = give(NN*4);
  size_t o_part     = give(512*4);
  size_t o_wt0=give(DD*DD*2), o_wq=give(DD*DD*2), o_wk=give(DD*DD*2), o_wv=give(DD*DD*2);
  size_t o_wg0=give(DD*DD*2), o_wgc=give(DD*DD*2), o_wo=give(DD*DOUT*2);
  size_t o_kvsT=give(DD*DD*2);
  size_t o_sc0=give(DD*4), o_sh0=give(DD*4), o_sc1=give(DD*4), o_sh1=give(DD*4);
  // zero region (contiguous): deg, gcur, kvs, ksum, vsum, cs0, cq0, cs1, cq1
  size_t o_zero = off;
  size_t o_deg = give(NN*4);
  size_t o_gcur = give(NBK*4);
  size_t o_kvs = give(DD*DD*4);
  size_t o_ksum=give(DD*4), o_vsum=give(DD*4);
  size_t o_cs0=give(DD*4), o_cq0=give(DD*4), o_cs1=give(DD*4), o_cq1=give(DD*4);
  size_t zero_len = off - o_zero;

  u16* B0=(u16*)(ws+o_b0); u16* B1=(u16*)(ws+o_b1); u16* B2=(u16*)(ws+o_b2);
  u16* B3=(u16*)(ws+o_b3); u16* B4=(u16*)(ws+o_b4);
  int* csr=(int*)(ws+o_csr); u32* brec=(u32*)(ws+o_brec);
  int* rowstart=(int*)(ws+o_rowstart);
  float* dsq=(float*)(ws+o_dsq); int* part=(int*)(ws+o_part);
  u16* wt0=(u16*)(ws+o_wt0); u16* wq=(u16*)(ws+o_wq); u16* wk=(u16*)(ws+o_wk); u16* wv=(u16*)(ws+o_wv);
  u16* wg0=(u16*)(ws+o_wg0); u16* wgc=(u16*)(ws+o_wgc); u16* wo=(u16*)(ws+o_wo);
  u16* kvsT=(u16*)(ws+o_kvsT);
  float* sc0=(float*)(ws+o_sc0); float* sh0=(float*)(ws+o_sh0);
  float* sc1=(float*)(ws+o_sc1); float* sh1=(float*)(ws+o_sh1);
  int* deg=(int*)(ws+o_deg); int* gcur=(int*)(ws+o_gcur); float* kvs=(float*)(ws+o_kvs);
  float* ksum=(float*)(ws+o_ksum); float* vsum=(float*)(ws+o_vsum);
  float* cs0=(float*)(ws+o_cs0); float* cq0=(float*)(ws+o_cq0);
  float* cs1=(float*)(ws+o_cs1); float* cq1=(float*)(ws+o_cq1);

  hipMemsetAsync(ws + o_zero, 0, zero_len, stream);

  // weights -> transposed bf16
  k_wtrans<<<256,256,0,stream>>>(tW0, wt0, 256);
  k_wtrans<<<256,256,0,stream>>>(Wq,  wq,  256);
  k_wtrans<<<256,256,0,stream>>>(Wk,  wk,  256);
  k_wtrans<<<256,256,0,stream>>>(Wv,  wv,  256);
  k_wtrans<<<256,256,0,stream>>>(gW0, wg0, 256);
  k_wtrans<<<256,256,0,stream>>>(gWc, wgc, 256);
  k_wtrans<<<128,256,0,stream>>>(Wo,  wo,  128);

  // graph CSR via bucket sort (write-locality instead of random scatter)
  k_bscat<<<391,256,0,stream>>>(ei, gcur, brec);
  k_bdeg<<<NBK,256,0,stream>>>(brec, gcur, deg);
  k_scan_a<<<391,256,0,stream>>>(deg, part);
  k_scan_b<<<1,512,0,stream>>>(part);
  k_scan_c<<<391,256,0,stream>>>(deg, part, rowstart, dsq);
  k_bcsr<<<NBK,256,0,stream>>>(brec, gcur, rowstart, csr);

  // x -> bf16 (stashed in B2; dead once LN+CS consumed it, then B2 becomes q)
  k_f2bv<<<12500,256,0,stream>>>(x, B2);

  const int TG = 512;   // persistent grid for k_ts
  // h = relu(LN(x@tW0+tb0))
  k_ts<EP_LN><<<TG,512,0,stream>>>(B2, wt0, tb0, B0, nullptr,
      tln0g, tln0b, nullptr, nullptr, nullptr, nullptr,
      nullptr, nullptr, nullptr, nullptr, nullptr);
  // yg = x@gW0+gb0 (+colstats)
  k_ts<EP_CS><<<TG,512,0,stream>>>(B2, wg0, gb0, B1, nullptr,
      nullptr, nullptr, nullptr, nullptr, nullptr, nullptr,
      nullptr, nullptr, nullptr, cs0, cq0);
  // q = rownorm(h@Wq+bq)  (B2 = xb dead -> reuse as q)
  k_ts<EP_QN><<<TG,512,0,stream>>>(B0, wq, bq, B2, nullptr,
      nullptr, nullptr, nullptr, nullptr, nullptr, nullptr,
      nullptr, nullptr, nullptr, nullptr, nullptr);
  // kT = rownorm(h@Wk+bk)^T  (+ksum)
  k_ts<EP_KT><<<TG,512,0,stream>>>(B0, wk, bk, B3, nullptr,
      nullptr, nullptr, nullptr, nullptr, nullptr, nullptr,
      nullptr, nullptr, nullptr, ksum, nullptr);
  // vT = (h@Wv+bv)^T  (+vsum)
  k_ts<EP_VT><<<TG,512,0,stream>>>(B0, wv, bvv, B4, nullptr,
      nullptr, nullptr, nullptr, nullptr, nullptr, nullptr,
      nullptr, nullptr, nullptr, vsum, nullptr);
  // kvs = k^T @ v  (split-K atomic fp32) — legacy engine
  k_gemm<EP_KV,false,256><<<dim3(4,98),256,0,stream>>>(B3, B4, nullptr, nullptr, kvs,
      32, NN, NN, NN, 256);
  k_wtrans<<<256,256,0,stream>>>(kvs, kvsT, 256);
  // BN0 -> g0
  k_bnprep<<<1,256,0,stream>>>(cs0, cq0, gbn0g, gbn0b, sc0, sh0);
  k_bnrelu<<<12500,256,0,stream>>>(B1, sc0, sh0, B3 /*reuse: g0 (kT consumed)*/);
  k_gather<<<12500,256,0,stream>>>(B3, rowstart, csr, dsq, B1 /*agg (yg dead)*/);
  // y2 = agg@gWc+gbc (+colstats)
  k_ts<EP_CS><<<TG,512,0,stream>>>(B1, wgc, gbc, B4 /*y2 (vT dead)*/, nullptr,
      nullptr, nullptr, nullptr, nullptr, nullptr, nullptr,
      nullptr, nullptr, nullptr, cs1, cq1);
  k_bnprep<<<1,256,0,stream>>>(cs1, cq1, gbn1g, gbn1b, sc1, sh1);
  // comb = 0.8*(relu(bn1(y2))+g0) + 0.2*relu(LN((q@kvs+nf*vsum)/(q@ksum+2nf)+h))
  k_ts<EP_AT><<<TG,512,0,stream>>>(B2, kvsT, nullptr, B1 /*comb (agg dead)*/, nullptr,
      tln1g, tln1b, ksum, vsum, sc1, sh1,
      B0 /*h*/, B4 /*y2*/, B3 /*g0*/, nullptr, nullptr);
  // out = comb @ Wo + bo
  k_ts<EP_OUTP><<<TG,512,0,stream>>>(B1 /*comb*/, wo, bo, nullptr, (float*)d_out,
      nullptr, nullptr, nullptr, nullptr, nullptr, nullptr,
      nullptr, nullptr, nullptr, nullptr, nullptr);
}

// Round 5
// 884.091 us; speedup vs baseline: 1.7627x; 1.0040x over previous
//
#include <hip/hip_runtime.h>
#include <hip/hip_bf16.h>

#define NN 100000
#define NEG 1600000
#define DD 256
#define DOUT 128
#define NTILES 3125   // 100000 / 32
#define NBK 782       // buckets: c>>7, 99999>>7 = 781
#define BCAP 2600     // per-bucket capacity (Poisson mean 2048, +12 sigma margin)
#define NNP 100096    // 64-aligned padded K for kT/vT (1564 * 64)
#define NKST 1564     // NNP / 64
#define SPB 13        // K-steps per k_kv block (128 chunks * 13 >= 1564)

typedef unsigned short u16;
typedef unsigned int u32;
typedef __attribute__((ext_vector_type(8))) __bf16 bf16x8;
typedef __attribute__((ext_vector_type(4))) float f32x4;
typedef __attribute__((ext_vector_type(4))) unsigned int u32x4;

__device__ __forceinline__ float b2f(u16 b){ u32 u=((u32)b)<<16; float f; __builtin_memcpy(&f,&u,4); return f; }
__device__ __forceinline__ u16 f2b(float f){ u32 u; __builtin_memcpy(&u,&f,4); u32 r=(u + 0x7FFFu + ((u>>16)&1u))>>16; return (u16)r; }
__device__ __forceinline__ u32 pack2(float a, float b){ return (u32)f2b(a) | ((u32)f2b(b)<<16); }

template<int N>
__device__ __forceinline__ void s_wait_vm(){
  asm volatile("s_waitcnt vmcnt(%0)" :: "n"(N) : "memory");
  __builtin_amdgcn_sched_barrier(0);
}
__device__ __forceinline__ void tile_barrier(){
  __builtin_amdgcn_s_barrier();
  __builtin_amdgcn_sched_barrier(0);
}
__device__ __forceinline__ void wave_barrier(){
  asm volatile("s_waitcnt lgkmcnt(0)" ::: "memory");
  __builtin_amdgcn_sched_barrier(0);
  __builtin_amdgcn_s_barrier();
  __builtin_amdgcn_sched_barrier(0);
}
__device__ __forceinline__ f32x4 mfma16(u32x4 a, u32x4 b, f32x4 c){
  return __builtin_amdgcn_mfma_f32_16x16x32_bf16(
    __builtin_bit_cast(bf16x8,a), __builtin_bit_cast(bf16x8,b), c, 0,0,0);
}

// ---------------- weight transpose (fp32 [256][ncols] -> bf16 [ncols][256]) ----------------
__global__ void k_wtrans(const float* __restrict__ W, u16* __restrict__ WT, int ncols){
  int n = blockIdx.x; int k = threadIdx.x;
  WT[n*DD + k] = f2b(W[k*ncols + n]);
}

// ---------------- fp32 -> bf16 bulk convert (x) ----------------
__global__ void k_f2bv(const float* __restrict__ in, u16* __restrict__ out){
  long long i = (long long)(blockIdx.x*256 + threadIdx.x) * 8;
  if(i >= (long long)NN*DD) return;
  float4 a = *(const float4*)&in[i];
  float4 b = *(const float4*)&in[i+4];
  uint4 sv;
  sv.x = pack2(a.x,a.y); sv.y = pack2(a.z,a.w);
  sv.z = pack2(b.x,b.y); sv.w = pack2(b.z,b.w);
  *(uint4*)&out[i] = sv;
}

// ---------------- zero the K-pad columns of kT/vT ----------------
__global__ void k_zpad(u16* __restrict__ kT, u16* __restrict__ vT){
  int row = blockIdx.x;      // 0..255
  int i = threadIdx.x;       // 0..95
  kT[(size_t)row*NNP + NN + i] = 0;
  vT[(size_t)row*NNP + NN + i] = 0;
}

// ---------------- graph prep: 2-level bucket sort -> sequential CSR scatter ----------------
__global__ __launch_bounds__(256)
void k_bscat(const int* __restrict__ ei, int* __restrict__ gcur, u32* __restrict__ brec){
  __shared__ int hist[NBK];
  __shared__ int wbase[NBK];
  const int tid = threadIdx.x;
  for(int i=tid;i<NBK;i+=256) hist[i]=0;
  __syncthreads();
  const int e0 = blockIdx.x*4096;
  int r[16], c[16];
  #pragma unroll
  for(int i=0;i<16;i++){
    int e = e0 + tid + i*256;
    bool ok = e < NEG;
    r[i] = ok ? ei[e] : -1;
    c[i] = ok ? ei[NEG+e] : 0;
    if(ok) atomicAdd(&hist[c[i]>>7], 1);
  }
  __syncthreads();
  for(int i=tid;i<NBK;i+=256){
    int n = hist[i];
    wbase[i] = (n>0) ? atomicAdd(&gcur[i], n) : 0;
  }
  __syncthreads();
  #pragma unroll
  for(int i=0;i<16;i++){
    if(r[i]>=0){
      int b = c[i]>>7;
      int rk = atomicSub(&hist[b],1) - 1;    // unique in-block rank
      brec[b*BCAP + wbase[b] + rk] = ((u32)(c[i]&127)<<17) | (u32)r[i];
    }
  }
}

__global__ __launch_bounds__(256)
void k_bdeg(const u32* __restrict__ brec, const int* __restrict__ gcur, int* __restrict__ deg){
  __shared__ int cnt[128];
  const int b = blockIdx.x, tid = threadIdx.x;
  if(tid<128) cnt[tid]=0;
  __syncthreads();
  const int n = gcur[b];
  for(int i=tid;i<n;i+=256) atomicAdd(&cnt[(brec[b*BCAP+i]>>17)&127], 1);
  __syncthreads();
  int node = b*128 + tid;
  if(tid<128 && node<NN) deg[node] = cnt[tid];
}

__global__ __launch_bounds__(256)
void k_bcsr(const u32* __restrict__ brec, const int* __restrict__ gcur,
            const int* __restrict__ rowstart, int* __restrict__ csr_row){
  __shared__ int cnt[128];
  __shared__ int base[128];
  const int b = blockIdx.x, tid = threadIdx.x;
  if(tid<128){
    cnt[tid]=0;
    int node = b*128 + tid;
    base[tid] = (node<NN) ? rowstart[node] : 0;
  }
  __syncthreads();
  const int n = gcur[b];
  for(int i=tid;i<n;i+=256){
    u32 rec = brec[b*BCAP+i];
    int lc = (rec>>17)&127;
    int rk = atomicAdd(&cnt[lc],1);
    csr_row[base[lc]+rk] = (int)(rec & 0x1FFFFu);
  }
}

__global__ void k_scan_a(const int* __restrict__ deg, int* __restrict__ part){
  __shared__ int s[256];
  int i = blockIdx.x*256 + threadIdx.x;
  int v = (i < NN) ? deg[i] : 0;
  s[threadIdx.x] = v; __syncthreads();
  for(int o=128;o>0;o>>=1){ if(threadIdx.x<o) s[threadIdx.x]+=s[threadIdx.x+o]; __syncthreads(); }
  if(threadIdx.x==0) part[blockIdx.x]=s[0];
}

__global__ void k_scan_b(int* __restrict__ part){
  __shared__ int s[512];
  int tx = threadIdx.x;
  int v = (tx < 391) ? part[tx] : 0;
  s[tx] = v; __syncthreads();
  for(int o=1;o<512;o<<=1){ int t=(tx>=o)?s[tx-o]:0; __syncthreads(); s[tx]+=t; __syncthreads(); }
  if(tx < 391) part[tx] = s[tx]-v;  // exclusive
}

__global__ void k_scan_c(const int* __restrict__ deg, const int* __restrict__ part,
                         int* __restrict__ rowstart, float* __restrict__ dsq){
  __shared__ int s[256];
  int tx = threadIdx.x;
  int i = blockIdx.x*256 + tx;
  int v = (i < NN) ? deg[i] : 0;
  s[tx]=v; __syncthreads();
  for(int o=1;o<256;o<<=1){ int t=(tx>=o)?s[tx-o]:0; __syncthreads(); s[tx]+=t; __syncthreads(); }
  int incl = s[tx];
  int base = part[blockIdx.x];
  if(i < NN){
    int excl = base + incl - v;
    rowstart[i]=excl;
    dsq[i] = (v>0) ? rsqrtf((float)v) : 0.f;
    if(i == NN-1) rowstart[NN] = base + incl;
  }
}

// ---------------- BN helpers ----------------
__global__ void k_bnprep(const float* __restrict__ cs, const float* __restrict__ cq,
                         const float* __restrict__ g, const float* __restrict__ b,
                         float* __restrict__ scale, float* __restrict__ shift){
  int c = threadIdx.x;
  float m = cs[c] * (1.0f/NN);
  float var = cq[c] * (1.0f/NN) - m*m;
  float rs = rsqrtf(var + 1e-5f);
  float sc = g[c]*rs;
  scale[c] = sc; shift[c] = b[c] - m*sc;
}

__global__ void k_bnrelu(const u16* __restrict__ yg, const float* __restrict__ scale,
                         const float* __restrict__ shift, u16* __restrict__ g0){
  long long i = (long long)(blockIdx.x*256 + threadIdx.x) * 8;
  if(i >= (long long)NN*DD) return;
  int c0 = (int)(i & 255);
  uint4 v = *(const uint4*)&yg[i];
  const u16* p = (const u16*)&v;
  u32 w[4];
  #pragma unroll
  for(int j=0;j<4;j++){
    float a = fmaxf(b2f(p[2*j  ])*scale[c0+2*j  ]+shift[c0+2*j  ], 0.f);
    float b_ = fmaxf(b2f(p[2*j+1])*scale[c0+2*j+1]+shift[c0+2*j+1], 0.f);
    w[j] = pack2(a,b_);
  }
  uint4 sv; sv.x=w[0]; sv.y=w[1]; sv.z=w[2]; sv.w=w[3];
  *(uint4*)&g0[i] = sv;
}

// ---------------- CSR gather (4-way edge unroll for MLP) ----------------
__global__ __launch_bounds__(256) void k_gather(const u16* __restrict__ g0, const int* __restrict__ rowstart,
                                                const int* __restrict__ csr_row, const float* __restrict__ dsq,
                                                u16* __restrict__ agg){
  int node = blockIdx.x*8 + (threadIdx.x>>5);
  int lane = threadIdx.x & 31;
  if(node >= NN) return;
  int s = rowstart[node], e = rowstart[node+1];
  float di = dsq[node];
  int d0 = lane*8;
  float acc[8] = {0,0,0,0,0,0,0,0};
  int j = s;
  for(; j+3 < e; j += 4){
    int r0 = csr_row[j], r1 = csr_row[j+1], r2 = csr_row[j+2], r3 = csr_row[j+3];
    float w0 = di*dsq[r0], w1 = di*dsq[r1], w2 = di*dsq[r2], w3 = di*dsq[r3];
    uint4 a = *(const uint4*)&g0[(size_t)r0*DD + d0];
    uint4 b = *(const uint4*)&g0[(size_t)r1*DD + d0];
    uint4 c = *(const uint4*)&g0[(size_t)r2*DD + d0];
    uint4 d = *(const uint4*)&g0[(size_t)r3*DD + d0];
    const u16* pa=(const u16*)&a; const u16* pb=(const u16*)&b;
    const u16* pc=(const u16*)&c; const u16* pd=(const u16*)&d;
    #pragma unroll
    for(int t=0;t<8;t++){
      acc[t] += w0*b2f(pa[t]); acc[t] += w1*b2f(pb[t]);
      acc[t] += w2*b2f(pc[t]); acc[t] += w3*b2f(pd[t]);
    }
  }
  for(; j < e; j++){
    int r0 = csr_row[j]; float w0 = di*dsq[r0];
    uint4 a = *(const uint4*)&g0[(size_t)r0*DD + d0];
    const u16* pa = (const u16*)&a;
    #pragma unroll
    for(int t=0;t<8;t++) acc[t] += w0*b2f(pa[t]);
  }
  u32 w[4];
  #pragma unroll
  for(int t=0;t<4;t++) w[t] = pack2(acc[2*t], acc[2*t+1]);
  uint4 sv; sv.x=w[0]; sv.y=w[1]; sv.z=w[2]; sv.w=w[3];
  *(uint4*)&agg[(size_t)node*DD + d0] = sv;
}

enum { EP_LN=0, EP_QN=1, EP_KT=2, EP_VT=3, EP_CS=4, EP_AT=5, EP_OUTP=6 };

// ---------------- streaming split-K GEMM: kvs[256][256] = kT[256][NNP] @ vT[256][NNP]^T ----------------
// 512 blocks = 4 M-tiles x 128 K-chunks of SPB*64 elems. Per K-step (64):
// stage As[64][64] + Bs[256][64] (40 KB) via global_load_lds, 5 issues/wave
// uniformly, counted vmcnt(5). XOR swizzle (slot^row&7) on src + read -> 2-way
// conflicts (free). fp32 atomicAdd epilogue.
__global__ __launch_bounds__(512,2)
void k_kv(const u16* __restrict__ kT, const u16* __restrict__ vT, float* __restrict__ kvs)
{
  const int tid = threadIdx.x;
  const int wave = tid>>6, lane = tid&63, quad = lane>>4, l15 = lane&15;
  const int bx = blockIdx.x & 3, by = blockIdx.x >> 2;
  const int m0 = bx*64;
  const int wb = wave*32;

  const int st0 = by*SPB;
  const int nst = min(SPB, NKST - st0);
  if(nst <= 0) return;
  const int kw0 = st0*64;

  __shared__ __align__(16) u16 As[2][4096];    // [64][64] per buf, 8 KB
  __shared__ __align__(16) u16 Bs[2][16384];   // [256][64] per buf, 32 KB

  auto stage = [&](int buf, int kb){
    #pragma unroll
    for(int i=0;i<5;i++){
      int c = wave*5 + i;                      // 40 chunks of 1 KB: 0-7 As, 8-39 Bs
      int lrow = ((c<8) ? c*8 : (c-8)*8) + (lane>>3);
      int slot = lane & 7;
      int srcslot = slot ^ (lrow & 7);
      const char* g; u16* lp;
      if(c < 8){
        g = (const char*)kT + ((size_t)(m0+lrow)*NNP + (size_t)kb)*2 + srcslot*16;
        lp = &As[buf][c*512];
      } else {
        g = (const char*)vT + ((size_t)lrow*NNP + (size_t)kb)*2 + srcslot*16;
        lp = &Bs[buf][(c-8)*512];
      }
      __builtin_amdgcn_global_load_lds(
        (const __attribute__((address_space(1))) unsigned int*)g,
        (__attribute__((address_space(3))) unsigned int*)lp, 16, 0, 0);
    }
  };
  auto ldA = [&](int buf, int mi, int kk)->u32x4{
    int row = mi*16 + l15;
    int slot = (kk*4 + quad) ^ (row & 7);
    return *(const u32x4*)((const char*)&As[buf][0] + row*128 + slot*16);
  };
  auto ldB = [&](int buf, int ni, int kk)->u32x4{
    int row = wb + ni*16 + l15;
    int slot = (kk*4 + quad) ^ (row & 7);
    return *(const u32x4*)((const char*)&Bs[buf][0] + row*128 + slot*16);
  };

  f32x4 acc[4][2];
  #pragma unroll
  for(int mi=0;mi<4;mi++)
    #pragma unroll
    for(int ni=0;ni<2;ni++){ acc[mi][ni][0]=0.f; acc[mi][ni][1]=0.f; acc[mi][ni][2]=0.f; acc[mi][ni][3]=0.f; }

  int cur = 0;
  stage(0, kw0);
  for(int st=0; st<nst; st++){
    if(st+1 < nst){ stage(cur^1, kw0 + (st+1)*64); s_wait_vm<5>(); }
    else          { s_wait_vm<0>(); }
    tile_barrier();
    #pragma unroll
    for(int kk=0;kk<2;kk++){
      u32x4 b0 = ldB(cur,0,kk), b1 = ldB(cur,1,kk);
      #pragma unroll
      for(int mi=0;mi<4;mi++){
        u32x4 a = ldA(cur,mi,kk);
        acc[mi][0] = mfma16(a, b0, acc[mi][0]);
        acc[mi][1] = mfma16(a, b1, acc[mi][1]);
      }
    }
    tile_barrier();                            // all reads of buf done before re-stage
    cur ^= 1;
  }

  #pragma unroll
  for(int mi=0;mi<4;mi++)
    #pragma unroll
    for(int r=0;r<4;r++){
      int gm = m0 + mi*16 + quad*4 + r;
      atomicAdd(&kvs[(size_t)gm*DD + wb + l15],      acc[mi][0][r]);
      atomicAdd(&kvs[(size_t)gm*DD + wb + 16 + l15], acc[mi][1][r]);
    }
}

// ---------------- tile-streaming GEMM engine ----------------
template<int EP>
__global__ __launch_bounds__(512,2)
void k_ts(const u16* __restrict__ Ab, const u16* __restrict__ BT,
          const float* __restrict__ bias,
          u16* __restrict__ outb, float* __restrict__ outf,
          const float* __restrict__ p0, const float* __restrict__ p1,
          const float* __restrict__ p2, const float* __restrict__ p3,
          const float* __restrict__ p4, const float* __restrict__ p5,
          const u16* __restrict__ hb, const u16* __restrict__ y2b, const u16* __restrict__ g0b,
          float* __restrict__ st0, float* __restrict__ st1)
{
  constexpr bool TRS = (EP==EP_KT||EP==EP_VT);
  constexpr int NCW = (EP==EP_OUTP)?16:32;   // cols per wave
  const int tid = threadIdx.x;
  const int wave = tid>>6, lane = tid&63, quad = lane>>4, l15 = lane&15;
  const int wb = wave*NCW;
  const int col0 = wb+l15, col1 = wb+16+l15;   // col1 unused when NCW==16

  __shared__ __align__(16) u16 As[2][8192];    // 2 x 16 KB
  __shared__ float red[2][2][8][16];
  __shared__ float dls[2][16];
  __shared__ u16 Ts[TRS?32:1][TRS?266:1];      // 266: odd dword stride -> conflict-free col read

  // ---- B panel resident in VGPRs ----
  u32x4 bf0[8], bf1[8];
  {
    const u16* b0p = &BT[(size_t)col0*DD + quad*8];
    #pragma unroll
    for(int ks=0;ks<8;ks++) bf0[ks]=*(const u32x4*)(b0p+ks*32);
    if constexpr (NCW==32){
      const u16* b1p = &BT[(size_t)col1*DD + quad*8];
      #pragma unroll
      for(int ks=0;ks<8;ks++) bf1[ks]=*(const u32x4*)(b1p+ks*32);
    }
  }
  float bv0 = bias? bias[col0]:0.f;
  float bv1 = (NCW==32 && bias)? bias[col1]:0.f;
  float g0c=0.f,g1c=0.f,b0c=0.f,b1c=0.f;
  if constexpr (EP==EP_LN||EP==EP_AT){ g0c=p0[col0]; g1c=p0[col1]; b0c=p1[col0]; b1c=p1[col1]; }
  float vs0=0.f, vs1=0.f, sc1a=0.f, sc1b=0.f, sh1a=0.f, sh1b=0.f;
  if constexpr (EP==EP_AT){
    vs0=p3[col0]; vs1=p3[col1];
    sc1a=p4[col0]; sc1b=p4[col1]; sh1a=p5[col0]; sh1b=p5[col1];
  }

  float csA=0.f,csB=0.f,cqA=0.f,cqB=0.f;   // cross-tile col-stat accumulators

  auto stage = [&](int buf, int t){
    #pragma unroll
    for(int it=0; it<2; it++){
      int c = wave + it*8;                 // 1 KB chunk id, wave-uniform
      int row = 2*c + (lane>>5);
      int colb = (lane&31)*16;
      int srcb = colb ^ ((row&7)<<4);      // involution swizzle
      const char* g = (const char*)Ab + ((size_t)t*32 + row)*512 + srcb;
      u16* lp = &As[buf][c*512];           // wave-uniform LDS base; HW adds lane*16
      __builtin_amdgcn_global_load_lds(
        (const __attribute__((address_space(1))) unsigned int*)g,
        (__attribute__((address_space(3))) unsigned int*)lp, 16, 0, 0);
    }
  };
  const char* lbase = (const char*)&As[0][0];
  auto ldfrag = [&](int buf, int mi, int ks)->u32x4{
    int row = mi*16 + l15;
    int cb = (ks*64 + quad*16) ^ ((row&7)<<4);
    return *(const u32x4*)(lbase + buf*16384 + row*512 + cb);
  };

  int t = blockIdx.x;
  int cur = 0;
  if(t < NTILES) stage(0, t);
  for(; t < NTILES; t += gridDim.x){
    int tn = t + (int)gridDim.x;
    if(tn < NTILES){ stage(cur^1, tn); s_wait_vm<2>(); }
    else           { s_wait_vm<0>(); }
    tile_barrier();                        // As[cur] fully staged for all waves

    #pragma unroll
    for(int mi=0; mi<2; mi++){
      const int slot = mi;
      u32x4 fr[8];
      #pragma unroll
      for(int ks=0;ks<8;ks++) fr[ks]=ldfrag(cur,mi,ks);
      f32x4 a0={0.f,0.f,0.f,0.f}, a1={0.f,0.f,0.f,0.f};
      #pragma unroll
      for(int ks=0;ks<8;ks++){
        a0=mfma16(fr[ks],bf0[ks],a0);
        if constexpr (NCW==32) a1=mfma16(fr[ks],bf1[ks],a1);
      }
      const int rbase = t*32 + mi*16;

      if constexpr (EP==EP_OUTP){
        #pragma unroll
        for(int r=0;r<4;r++){
          int gr = rbase + quad*4 + r;
          outf[(size_t)gr*DOUT + col0] = a0[r] + bv0;
        }
      }
      if constexpr (EP==EP_CS){
        #pragma unroll
        for(int r=0;r<4;r++){
          int gr = rbase + quad*4 + r;
          float v0=a0[r]+bv0, v1=a1[r]+bv1;
          outb[(size_t)gr*DD+col0]=f2b(v0);
          outb[(size_t)gr*DD+col1]=f2b(v1);
          csA+=v0; cqA+=v0*v0; csB+=v1; cqB+=v1*v1;
        }
      }
      if constexpr (EP==EP_VT){
        #pragma unroll
        for(int r=0;r<4;r++){
          int row=quad*4+r;
          float v0=a0[r]+bv0, v1=a1[r]+bv1;
          csA+=v0; csB+=v1;
          Ts[mi*16+row][col0]=f2b(v0);
          Ts[mi*16+row][col1]=f2b(v1);
        }
      }
      if constexpr (EP==EP_QN||EP==EP_KT){
        #pragma unroll
        for(int r=0;r<4;r++){
          float v0=a0[r]+bv0, v1=a1[r]+bv1;
          float s2=v0*v0+v1*v1;
          #pragma unroll
          for(int o=1;o<16;o<<=1) s2+=__shfl_xor(s2,o);
          if(l15==0) red[slot][0][wave][quad*4+r]=s2;
        }
        wave_barrier();
        #pragma unroll
        for(int r=0;r<4;r++){
          int row=quad*4+r, gr=rbase+row;
          float S2=0.f;
          #pragma unroll
          for(int w=0;w<8;w++) S2+=red[slot][0][w][row];
          float rsr=rsqrtf(S2);
          if constexpr (EP==EP_QN){
            outb[(size_t)gr*DD+col0]=f2b((a0[r]+bv0)*rsr);
            outb[(size_t)gr*DD+col1]=f2b((a1[r]+bv1)*rsr);
          } else {
            float v0=(a0[r]+bv0)*rsr, v1=(a1[r]+bv1)*rsr;
            csA+=v0; csB+=v1;
            Ts[mi*16+row][col0]=f2b(v0);
            Ts[mi*16+row][col1]=f2b(v1);
          }
        }
      }
      if constexpr (EP==EP_AT){
        float dv=0.f;
        #pragma unroll
        for(int ks=0;ks<8;ks++){
          const u16* ax=(const u16*)&fr[ks];
          #pragma unroll
          for(int j=0;j<8;j++) dv += b2f(ax[j]) * p2[ks*32+quad*8+j];
        }
        dv += __shfl_xor(dv,16); dv += __shfl_xor(dv,32);
        if(wave==0 && quad==0) dls[slot][l15]=dv+200000.0f;   // + 2*nf
        wave_barrier();
        float vv0[4], vv1[4];
        #pragma unroll
        for(int r=0;r<4;r++){
          int row=quad*4+r, gr=rbase+row;
          float den=dls[slot][row];
          size_t rb=(size_t)gr*DD;
          float hv0=b2f(hb[rb+col0]), hv1=b2f(hb[rb+col1]);
          vv0[r]=((a0[r]+100000.0f*vs0)/den + hv0)*0.5f;
          vv1[r]=((a1[r]+100000.0f*vs1)/den + hv1)*0.5f;
        }
        #pragma unroll
        for(int r=0;r<4;r++){
          float s=vv0[r]+vv1[r], s2=vv0[r]*vv0[r]+vv1[r]*vv1[r];
          #pragma unroll
          for(int o=1;o<16;o<<=1){ s+=__shfl_xor(s,o); s2+=__shfl_xor(s2,o); }
          if(l15==0){ red[slot][0][wave][quad*4+r]=s; red[slot][1][wave][quad*4+r]=s2; }
        }
        wave_barrier();
        #pragma unroll
        for(int r=0;r<4;r++){
          int row=quad*4+r, gr=rbase+row;
          float S=0.f,S2=0.f;
          #pragma unroll
          for(int w=0;w<8;w++){ S+=red[slot][0][w][row]; S2+=red[slot][1][w][row]; }
          float mean=S*(1.0f/DD), var=S2*(1.0f/DD)-mean*mean, rstd=rsqrtf(var+1e-5f);
          float x10=fmaxf((vv0[r]-mean)*rstd*g0c+b0c, 0.f);
          float x11=fmaxf((vv1[r]-mean)*rstd*g1c+b1c, 0.f);
          // fuse: comb = 0.8*(relu(bn1(y2))+g0) + 0.2*x1
          size_t rb=(size_t)gr*DD;
          float x20=fmaxf(sc1a*b2f(y2b[rb+col0])+sh1a,0.f)+b2f(g0b[rb+col0]);
          float x21=fmaxf(sc1b*b2f(y2b[rb+col1])+sh1b,0.f)+b2f(g0b[rb+col1]);
          outb[rb+col0]=f2b(0.8f*x20+0.2f*x10);
          outb[rb+col1]=f2b(0.8f*x21+0.2f*x11);
        }
      }
      if constexpr (EP==EP_LN){
        #pragma unroll
        for(int r=0;r<4;r++){
          float v0=a0[r]+bv0, v1=a1[r]+bv1;
          float s=v0+v1, s2=v0*v0+v1*v1;
          #pragma unroll
          for(int o=1;o<16;o<<=1){ s+=__shfl_xor(s,o); s2+=__shfl_xor(s2,o); }
          if(l15==0){ red[slot][0][wave][quad*4+r]=s; red[slot][1][wave][quad*4+r]=s2; }
        }
        wave_barrier();
        #pragma unroll
        for(int r=0;r<4;r++){
          int row=quad*4+r, gr=rbase+row;
          float S=0.f,S2=0.f;
          #pragma unroll
          for(int w=0;w<8;w++){ S+=red[slot][0][w][row]; S2+=red[slot][1][w][row]; }
          float mean=S*(1.0f/DD), var=S2*(1.0f/DD)-mean*mean, rstd=rsqrtf(var+1e-5f);
          float v0=(a0[r]+bv0-mean)*rstd*g0c+b0c;
          float v1=(a1[r]+bv1-mean)*rstd*g1c+b1c;
          outb[(size_t)gr*DD+col0]=f2b(fmaxf(v0,0.f));
          outb[(size_t)gr*DD+col1]=f2b(fmaxf(v1,0.f));
        }
      }
    }

    if constexpr (TRS){
      wave_barrier();                      // all Ts writes visible
      int gcol = t*32 + (lane&31);
      int dbv = wb + (lane>>5)*16;
      #pragma unroll
      for(int dd=0;dd<16;dd++)
        outb[(size_t)(dbv+dd)*NNP + gcol] = Ts[lane&31][dbv+dd];
    }

    wave_barrier();                        // all reads of As[cur] (and Ts) done
    cur ^= 1;
  }

  if constexpr (EP==EP_CS){
    float c,q;
    c=csA; q=cqA; c+=__shfl_xor(c,16); c+=__shfl_xor(c,32); q+=__shfl_xor(q,16); q+=__shfl_xor(q,32);
    if(quad==0){ atomicAdd(&st0[col0],c); atomicAdd(&st1[col0],q); }
    c=csB; q=cqB; c+=__shfl_xor(c,16); c+=__shfl_xor(c,32); q+=__shfl_xor(q,16); q+=__shfl_xor(q,32);
    if(quad==0){ atomicAdd(&st0[col1],c); atomicAdd(&st1[col1],q); }
  }
  if constexpr (TRS){
    float c;
    c=csA; c+=__shfl_xor(c,16); c+=__shfl_xor(c,32);
    if(quad==0) atomicAdd(&st0[col0],c);
    c=csB; c+=__shfl_xor(c,16); c+=__shfl_xor(c,32);
    if(quad==0) atomicAdd(&st0[col1],c);
  }
}

// ---------------- launch ----------------
extern "C" void kernel_launch(void* const* d_in, const int* in_sizes, int n_in,
                              void* d_out, int out_size, void* d_ws, size_t ws_size,
                              hipStream_t stream) {
  (void)in_sizes; (void)n_in; (void)out_size; (void)ws_size;
  const float* x     = (const float*)d_in[0];
  const int*   ei    = (const int*)d_in[1];
  const float* tW0   = (const float*)d_in[2];
  const float* tb0   = (const float*)d_in[3];
  const float* tln0g = (const float*)d_in[4];
  const float* tln0b = (const float*)d_in[5];
  const float* Wq    = (const float*)d_in[6];
  const float* bq    = (const float*)d_in[7];
  const float* Wk    = (const float*)d_in[8];
  const float* bk    = (const float*)d_in[9];
  const float* Wv    = (const float*)d_in[10];
  const float* bvv   = (const float*)d_in[11];
  const float* tln1g = (const float*)d_in[12];
  const float* tln1b = (const float*)d_in[13];
  const float* gW0   = (const float*)d_in[14];
  const float* gb0   = (const float*)d_in[15];
  const float* gbn0g = (const float*)d_in[16];
  const float* gbn0b = (const float*)d_in[17];
  const float* gWc   = (const float*)d_in[18];
  const float* gbc   = (const float*)d_in[19];
  const float* gbn1g = (const float*)d_in[20];
  const float* gbn1b = (const float*)d_in[21];
  const float* Wo    = (const float*)d_in[22];
  const float* bo    = (const float*)d_in[23];

  char* ws = (char*)d_ws;
  size_t off = 0;
  auto give = [&](size_t b){ size_t o = off; off += (b + 511) & ~(size_t)511; return o; };
  const size_t NB = (size_t)NNP*DD*2;   // 51.25 MB bf16 buffer (padded stride capable)
  size_t o_b0=give(NB), o_b1=give(NB), o_b2=give(NB), o_b3=give(NB), o_b4=give(NB);
  size_t o_csr = give((size_t)NEG*4);
  size_t o_brec = give((size_t)NBK*BCAP*4);
  size_t o_rowstart = give((NN+1)*4);
  size_t o_dsq      = give(NN*4);
  size_t o_part     = give(512*4);
  size_t o_wt0=give(DD*DD*2), o_wq=give(DD*DD*2), o_wk=give(DD*DD*2), o_wv=give(DD*DD*2);
  size_t o_wg0=give(DD*DD*2), o_wgc=give(DD*DD*2), o_wo=give(DD*DOUT*2);
  size_t o_kvsT=give(DD*DD*2);
  size_t o_sc0=give(DD*4), o_sh0=give(DD*4), o_sc1=give(DD*4), o_sh1=give(DD*4);
  // zero region (contiguous): deg, gcur, kvs, ksum, vsum, cs0, cq0, cs1, cq1
  size_t o_zero = off;
  size_t o_deg = give(NN*4);
  size_t o_gcur = give(NBK*4);
  size_t o_kvs = give(DD*DD*4);
  size_t o_ksum=give(DD*4), o_vsum=give(DD*4);
  size_t o_cs0=give(DD*4), o_cq0=give(DD*4), o_cs1=give(DD*4), o_cq1=give(DD*4);
  size_t zero_len = off - o_zero;

  u16* B0=(u16*)(ws+o_b0); u16* B1=(u16*)(ws+o_b1); u16* B2=(u16*)(ws+o_b2);
  u16* B3=(u16*)(ws+o_b3); u16* B4=(u16*)(ws+o_b4);
  int* csr=(int*)(ws+o_csr); u32* brec=(u32*)(ws+o_brec);
  int* rowstart=(int*)(ws+o_rowstart);
  float* dsq=(float*)(ws+o_dsq); int* part=(int*)(ws+o_part);
  u16* wt0=(u16*)(ws+o_wt0); u16* wq=(u16*)(ws+o_wq); u16* wk=(u16*)(ws+o_wk); u16* wv=(u16*)(ws+o_wv);
  u16* wg0=(u16*)(ws+o_wg0); u16* wgc=(u16*)(ws+o_wgc); u16* wo=(u16*)(ws+o_wo);
  u16* kvsT=(u16*)(ws+o_kvsT);
  float* sc0=(float*)(ws+o_sc0); float* sh0=(float*)(ws+o_sh0);
  float* sc1=(float*)(ws+o_sc1); float* sh1=(float*)(ws+o_sh1);
  int* deg=(int*)(ws+o_deg); int* gcur=(int*)(ws+o_gcur); float* kvs=(float*)(ws+o_kvs);
  float* ksum=(float*)(ws+o_ksum); float* vsum=(float*)(ws+o_vsum);
  float* cs0=(float*)(ws+o_cs0); float* cq0=(float*)(ws+o_cq0);
  float* cs1=(float*)(ws+o_cs1); float* cq1=(float*)(ws+o_cq1);

  hipMemsetAsync(ws + o_zero, 0, zero_len, stream);

  // weights -> transposed bf16
  k_wtrans<<<256,256,0,stream>>>(tW0, wt0, 256);
  k_wtrans<<<256,256,0,stream>>>(Wq,  wq,  256);
  k_wtrans<<<256,256,0,stream>>>(Wk,  wk,  256);
  k_wtrans<<<256,256,0,stream>>>(Wv,  wv,  256);
  k_wtrans<<<256,256,0,stream>>>(gW0, wg0, 256);
  k_wtrans<<<256,256,0,stream>>>(gWc, wgc, 256);
  k_wtrans<<<128,256,0,stream>>>(Wo,  wo,  128);

  // graph CSR via bucket sort (write-locality instead of random scatter)
  k_bscat<<<391,256,0,stream>>>(ei, gcur, brec);
  k_bdeg<<<NBK,256,0,stream>>>(brec, gcur, deg);
  k_scan_a<<<391,256,0,stream>>>(deg, part);
  k_scan_b<<<1,512,0,stream>>>(part);
  k_scan_c<<<391,256,0,stream>>>(deg, part, rowstart, dsq);
  k_bcsr<<<NBK,256,0,stream>>>(brec, gcur, rowstart, csr);

  // x -> bf16 (stashed in B2; dead once LN+CS consumed it, then B2 becomes q)
  k_f2bv<<<12500,256,0,stream>>>(x, B2);
  // zero kT/vT pad columns [NN, NNP)
  k_zpad<<<256,96,0,stream>>>(B3, B4);

  const int TG = 512;   // persistent grid for k_ts
  // h = relu(LN(x@tW0+tb0))
  k_ts<EP_LN><<<TG,512,0,stream>>>(B2, wt0, tb0, B0, nullptr,
      tln0g, tln0b, nullptr, nullptr, nullptr, nullptr,
      nullptr, nullptr, nullptr, nullptr, nullptr);
  // yg = x@gW0+gb0 (+colstats)
  k_ts<EP_CS><<<TG,512,0,stream>>>(B2, wg0, gb0, B1, nullptr,
      nullptr, nullptr, nullptr, nullptr, nullptr, nullptr,
      nullptr, nullptr, nullptr, cs0, cq0);
  // q = rownorm(h@Wq+bq)  (B2 = xb dead -> reuse as q)
  k_ts<EP_QN><<<TG,512,0,stream>>>(B0, wq, bq, B2, nullptr,
      nullptr, nullptr, nullptr, nullptr, nullptr, nullptr,
      nullptr, nullptr, nullptr, nullptr, nullptr);
  // kT = rownorm(h@Wk+bk)^T  (+ksum)   [stride NNP]
  k_ts<EP_KT><<<TG,512,0,stream>>>(B0, wk, bk, B3, nullptr,
      nullptr, nullptr, nullptr, nullptr, nullptr, nullptr,
      nullptr, nullptr, nullptr, ksum, nullptr);
  // vT = (h@Wv+bv)^T  (+vsum)          [stride NNP]
  k_ts<EP_VT><<<TG,512,0,stream>>>(B0, wv, bvv, B4, nullptr,
      nullptr, nullptr, nullptr, nullptr, nullptr, nullptr,
      nullptr, nullptr, nullptr, vsum, nullptr);
  // kvs = kT @ vT^T  (streaming split-K, fp32 atomics)
  k_kv<<<512,512,0,stream>>>(B3, B4, kvs);
  k_wtrans<<<256,256,0,stream>>>(kvs, kvsT, 256);
  // BN0 -> g0
  k_bnprep<<<1,256,0,stream>>>(cs0, cq0, gbn0g, gbn0b, sc0, sh0);
  k_bnrelu<<<12500,256,0,stream>>>(B1, sc0, sh0, B3 /*reuse: g0 (kT consumed)*/);
  k_gather<<<12500,256,0,stream>>>(B3, rowstart, csr, dsq, B1 /*agg (yg dead)*/);
  // y2 = agg@gWc+gbc (+colstats)
  k_ts<EP_CS><<<TG,512,0,stream>>>(B1, wgc, gbc, B4 /*y2 (vT dead)*/, nullptr,
      nullptr, nullptr, nullptr, nullptr, nullptr, nullptr,
      nullptr, nullptr, nullptr, cs1, cq1);
  k_bnprep<<<1,256,0,stream>>>(cs1, cq1, gbn1g, gbn1b, sc1, sh1);
  // comb = 0.8*(relu(bn1(y2))+g0) + 0.2*relu(LN((q@kvs+nf*vsum)/(q@ksum+2nf)+h))
  k_ts<EP_AT><<<TG,512,0,stream>>>(B2, kvsT, nullptr, B1 /*comb (agg dead)*/, nullptr,
      tln1g, tln1b, ksum, vsum, sc1, sh1,
      B0 /*h*/, B4 /*y2*/, B3 /*g0*/, nullptr, nullptr);
  // out = comb @ Wo + bo
  k_ts<EP_OUTP><<<TG,512,0,stream>>>(B1 /*comb*/, wo, bo, nullptr, (float*)d_out,
      nullptr, nullptr, nullptr, nullptr, nullptr, nullptr,
      nullptr, nullptr, nullptr, nullptr, nullptr);
}